// Round 2
// baseline (70023.749 us; speedup 1.0000x reference)
//
#include <hip/hip_runtime.h>
#include <cstdint>
#include <cstddef>

// ============================================================================
// 4-layer LSTM (B=128, T=1024, D=128, H={100,100,200,200}) + linear head.
// Time-chunked to fit workspace: per chunk of CT steps, run
//   gemm_pregate(L) -> lstm_rec(L)  for L = 0..3   (stream-serialized)
// lstm_rec persists c-state / h-state / flags in ws across chunk launches.
// All matmul math is bf16x3 (hi*hi + lo*hi + hi*lo) accumulated fp32.
// ============================================================================

#define AGENT __HIP_MEMORY_SCOPE_AGENT

typedef __attribute__((ext_vector_type(8))) short  short8;
typedef __attribute__((ext_vector_type(4))) float  f32x4;

struct us4 { unsigned short x, y, z, w; };

__device__ __forceinline__ unsigned short f2bf(float x){
  unsigned u = __float_as_uint(x);
  unsigned r = u + 0x7FFFu + ((u >> 16) & 1u);   // RN-even to bf16
  return (unsigned short)(r >> 16);
}
__device__ __forceinline__ float bf2f(unsigned short h){
  return __uint_as_float(((unsigned)h) << 16);
}
__device__ __forceinline__ float sigmoidf_(float x){ return 1.f / (1.f + __expf(-x)); }

// ---------------------------------------------------------------------------
// K1: pregate GEMM.  G[m][n] = sum_k A_row(m)[k]*W[k][n] + bias[n],
// m = t_local*128 + b, A_row(m) = A + (m>>7)*strideT + (m&127)*strideB.
// BM=256, BN=80, BK=32. bf16 hi/lo staged in LDS, 3 MFMAs per tile pair.
// ---------------------------------------------------------------------------
__global__ __launch_bounds__(256) void gemm_pregate(
    const float* __restrict__ A, const float* __restrict__ W,
    const float* __restrict__ bias, float* __restrict__ G,
    int K, int KT, int N, size_t strideT, size_t strideB)
{
  __shared__ unsigned short Ahi[256*40];
  __shared__ unsigned short Alo[256*40];
  __shared__ unsigned short Bhi[80*40];
  __shared__ unsigned short Blo[80*40];

  const int tid  = threadIdx.x;
  const int mb   = blockIdx.x;
  const int n0   = blockIdx.y * 80;
  const int wave = tid >> 6, lane = tid & 63;
  const int ln15 = lane & 15, quad = lane >> 4;

  f32x4 acc[4][5];
  for (int a = 0; a < 4; ++a)
    for (int b = 0; b < 5; ++b)
      acc[a][b] = (f32x4){0.f, 0.f, 0.f, 0.f};

  for (int kt = 0; kt < KT; ++kt){
    const int k0 = kt * 32;
    const bool full = (k0 + 31) < K;
    // stage A tile (256 rows x 32 k) as hi/lo bf16
    for (int i = 0; i < 8; ++i){
      const int e   = tid + 256*i;          // 2048 float4 slots
      const int row = e >> 3, seg = e & 7;
      const int mm  = mb*256 + row;
      const float* rp = A + (size_t)(mm >> 7)*strideT + (size_t)(mm & 127)*strideB;
      const int k = k0 + seg*4;
      float v0, v1, v2, v3;
      if (full){
        float4 v = *(const float4*)(rp + k);
        v0 = v.x; v1 = v.y; v2 = v.z; v3 = v.w;
      } else {
        v0 = (k+0 < K) ? rp[k+0] : 0.f;
        v1 = (k+1 < K) ? rp[k+1] : 0.f;
        v2 = (k+2 < K) ? rp[k+2] : 0.f;
        v3 = (k+3 < K) ? rp[k+3] : 0.f;
      }
      const unsigned short h0=f2bf(v0), h1=f2bf(v1), h2=f2bf(v2), h3=f2bf(v3);
      us4 hv{h0, h1, h2, h3};
      us4 lv{f2bf(v0-bf2f(h0)), f2bf(v1-bf2f(h1)), f2bf(v2-bf2f(h2)), f2bf(v3-bf2f(h3))};
      *(us4*)&Ahi[row*40 + seg*4] = hv;
      *(us4*)&Alo[row*40 + seg*4] = lv;
    }
    // stage B tile (32 k x 80 n) transposed to [n][k]
    for (int i = 0; i < 10; ++i){
      const int e  = tid + 256*i;           // 2560 elements
      const int kk = e / 80, nn = e - kk*80;
      const int k  = k0 + kk;
      const float v = (k < K) ? W[(size_t)k*N + n0 + nn] : 0.f;
      const unsigned short hb = f2bf(v);
      Bhi[nn*40 + kk] = hb;
      Blo[nn*40 + kk] = f2bf(v - bf2f(hb));
    }
    __syncthreads();
    short8 a_h[4], a_l[4];
    for (int mt = 0; mt < 4; ++mt){
      const int aoff = (wave*64 + mt*16 + ln15)*40 + quad*8;
      a_h[mt] = *(const short8*)&Ahi[aoff];
      a_l[mt] = *(const short8*)&Alo[aoff];
    }
    for (int nt = 0; nt < 5; ++nt){
      const int boff = (nt*16 + ln15)*40 + quad*8;
      const short8 b_h = *(const short8*)&Bhi[boff];
      const short8 b_l = *(const short8*)&Blo[boff];
      for (int mt = 0; mt < 4; ++mt){
        acc[mt][nt] = __builtin_amdgcn_mfma_f32_16x16x32_bf16(a_h[mt], b_h, acc[mt][nt], 0,0,0);
        acc[mt][nt] = __builtin_amdgcn_mfma_f32_16x16x32_bf16(a_l[mt], b_h, acc[mt][nt], 0,0,0);
        acc[mt][nt] = __builtin_amdgcn_mfma_f32_16x16x32_bf16(a_h[mt], b_l, acc[mt][nt], 0,0,0);
      }
    }
    __syncthreads();
  }
  for (int nt = 0; nt < 5; ++nt){
    const float bv = bias[n0 + nt*16 + ln15];
    for (int mt = 0; mt < 4; ++mt){
      const int mbase = mb*256 + wave*64 + mt*16 + quad*4;
      #pragma unroll
      for (int r = 0; r < 4; ++r)
        G[(size_t)(mbase + r)*N + n0 + nt*16 + ln15] = acc[mt][nt][r] + bv;
    }
  }
}

// ---------------------------------------------------------------------------
// K2: persistent grouped recurrence over steps [t0, t0+TC).
// Group = 8 blocks (blockIdx&7 == g) owning batch rows [16g,16g+16); member
// m = blockIdx>>3 owns hh in [m*HHM,(m+1)*HHM) across all 4 gates.
// Wh strip lives in LDS as bf16 hi/lo, [col][k] (B-operand layout).
// Per step: z = h_t @ Wh (bf16x3 MFMA) + G -> gates -> c,h update;
// h published as packed (hi<<16|lo) u32 via relaxed agent atomics; per-member
// flag (release) carries global step count; parity-2 Hx buffers by global t.
// c-state persists in ws across chunk launches.
// ---------------------------------------------------------------------------
template<int H, int P>
__global__ __launch_bounds__(256) void lstm_rec(
    const float* __restrict__ G, const float* __restrict__ Wh,
    unsigned* __restrict__ Hx, unsigned* __restrict__ flags,
    float* __restrict__ cstate, float* __restrict__ hseq_out,
    float* __restrict__ hlast, int t0, int TC, int Tlast)
{
  constexpr int HHM  = H / P;               // hidden units per member
  constexpr int COLS = 4 * HHM;             // real gate-cols per member
  constexpr int CP   = ((COLS + 15)/16)*16; // padded cols (MFMA N granularity)
  constexpr int KP   = ((H + 31)/32)*32;    // padded K (MFMA K granularity)
  constexpr int KSTR = KP + 8;              // LDS row stride (bank-conflict pad)
  constexpr int NT   = CP / 16;
  constexpr int KT   = KP / 32;
  constexpr int N4H  = 4 * H;
  constexpr int MAXNT = (NT + 3) / 4;

  extern __shared__ char smem[];
  unsigned short* whT_hi = (unsigned short*)smem;
  unsigned short* whT_lo = whT_hi + CP*KSTR;
  unsigned short* ah_hi  = whT_lo + CP*KSTR;
  unsigned short* ah_lo  = ah_hi  + 16*KSTR;
  float* zbuf = (float*)(ah_lo + 16*KSTR);  // [16][CP]
  float* gbuf = zbuf + 16*CP;               // [16][COLS]
  float* cbuf = gbuf + 16*COLS;             // [16][HHM]

  const int tid  = threadIdx.x;
  const int g    = blockIdx.x & 7;
  const int m    = blockIdx.x >> 3;
  const int row0 = g * 16;
  const int wave = tid >> 6, lane = tid & 63;
  const int ln15 = lane & 15, quad = lane >> 4;

  for (int e = tid; e < CP*KSTR; e += 256){ whT_hi[e] = 0; whT_lo[e] = 0; }
  // c-state: zero at t0==0, else resume from ws
  for (int e = tid; e < 16*HHM; e += 256){
    if (t0 == 0) cbuf[e] = 0.f;
    else {
      const int r = e / HHM, hh = e - r*HHM;
      cbuf[e] = cstate[(size_t)(row0 + r)*H + m*HHM + hh];
    }
  }
  __syncthreads();
  // load this member's Wh strip, transposed [col][k], hi/lo bf16
  for (int e = tid; e < H*COLS; e += 256){
    const int k = e / COLS, c = e - k*COLS;
    const int gate = c / HHM, hh = c - gate*HHM;
    const float w = Wh[(size_t)k*N4H + gate*H + m*HHM + hh];
    const unsigned short hi = f2bf(w);
    whT_hi[c*KSTR + k] = hi;
    whT_lo[c*KSTR + k] = f2bf(w - bf2f(hi));
  }
  __syncthreads();

  unsigned* flg = flags + g*8;

  for (int tl = 0; tl < TC; ++tl){
    const int t = t0 + tl;
    // stage G(t) for our rows/cols (independent of h -> before the flag wait)
    {
      const float* Gt = G + (size_t)tl * 128 * N4H;
      for (int e = tid; e < 16*COLS; e += 256){
        const int r = e / COLS, c = e - r*COLS;
        const int gate = c / HHM, hh = c - gate*HHM;
        gbuf[e] = Gt[(size_t)(row0 + r)*N4H + gate*H + m*HHM + hh];
      }
    }
    // wait until all members published h_t (flags >= t); bounded spin
    if (t > 0 && tid == 0){
      for (int j = 0; j < P; ++j){
        long spins = 0;
        while (__hip_atomic_load(&flg[j], __ATOMIC_ACQUIRE, AGENT) < (unsigned)t){
          if (++spins > (1L << 24)) break;   // safety: no infinite hang
        }
      }
    }
    __syncthreads();
    // stage h_t (full row tile) hi/lo into LDS A-operand layout
    {
      unsigned* src = Hx + (size_t)((t & 1)*8 + g) * 16 * 224;
      for (int e = tid; e < 16*KP; e += 256){
        const int r = e / KP, k = e - r*KP;
        const unsigned u = __hip_atomic_load(&src[r*224 + k], __ATOMIC_RELAXED, AGENT);
        ah_hi[r*KSTR + k] = (unsigned short)(u >> 16);
        ah_lo[r*KSTR + k] = (unsigned short)(u & 0xFFFFu);
      }
    }
    __syncthreads();
    // z = h_t @ Wh_strip  (bf16x3), n-tiles round-robin over 4 waves
    f32x4 acc[MAXNT];
    for (int i = 0; i < MAXNT; ++i) acc[i] = (f32x4){0.f,0.f,0.f,0.f};
    const int aoff = ln15*KSTR + quad*8;
    for (int kt = 0; kt < KT; ++kt){
      const int ko = kt*32;
      const short8 a_h = *(const short8*)&ah_hi[aoff + ko];
      const short8 a_l = *(const short8*)&ah_lo[aoff + ko];
      int ntl = 0;
      for (int nt = wave; nt < NT; nt += 4, ++ntl){
        const int boff = (nt*16 + ln15)*KSTR + quad*8 + ko;
        const short8 b_h = *(const short8*)&whT_hi[boff];
        const short8 b_l = *(const short8*)&whT_lo[boff];
        acc[ntl] = __builtin_amdgcn_mfma_f32_16x16x32_bf16(a_h, b_h, acc[ntl], 0,0,0);
        acc[ntl] = __builtin_amdgcn_mfma_f32_16x16x32_bf16(a_l, b_h, acc[ntl], 0,0,0);
        acc[ntl] = __builtin_amdgcn_mfma_f32_16x16x32_bf16(a_h, b_l, acc[ntl], 0,0,0);
      }
    }
    {
      int ntl = 0;
      for (int nt = wave; nt < NT; nt += 4, ++ntl)
        #pragma unroll
        for (int r = 0; r < 4; ++r)
          zbuf[(quad*4 + r)*CP + nt*16 + ln15] = acc[ntl][r];
    }
    __syncthreads();
    // gates, state update, publish h
    for (int e = tid; e < 16*HHM; e += 256){
      const int r = e / HHM, hh = e - r*HHM;
      const float zi = zbuf[r*CP + 0*HHM + hh] + gbuf[r*COLS + 0*HHM + hh];
      const float zf = zbuf[r*CP + 1*HHM + hh] + gbuf[r*COLS + 1*HHM + hh];
      const float zg = zbuf[r*CP + 2*HHM + hh] + gbuf[r*COLS + 2*HHM + hh];
      const float zo = zbuf[r*CP + 3*HHM + hh] + gbuf[r*COLS + 3*HHM + hh];
      const float c  = sigmoidf_(zf)*cbuf[e] + sigmoidf_(zi)*tanhf(zg);
      const float h  = sigmoidf_(zo)*tanhf(c);
      cbuf[e] = c;
      const unsigned short hhi = f2bf(h);
      const unsigned short hlo = f2bf(h - bf2f(hhi));
      const unsigned pk = ((unsigned)hhi << 16) | (unsigned)hlo;
      const int kidx = m*HHM + hh;
      __hip_atomic_store(&Hx[(size_t)(((t+1) & 1)*8 + g)*16*224 + r*224 + kidx],
                         pk, __ATOMIC_RELAXED, AGENT);
      if (hseq_out) hseq_out[((size_t)tl*128 + row0 + r)*(size_t)H + kidx] = h;
      if (hlast && t == Tlast-1) hlast[(size_t)(row0 + r)*H + kidx] = h;
    }
    __threadfence();
    __syncthreads();
    if (tid == 0)
      __hip_atomic_store(&flg[m], (unsigned)(t+1), __ATOMIC_RELEASE, AGENT);
  }
  // persist c-state for the next chunk
  __syncthreads();
  for (int e = tid; e < 16*HHM; e += 256){
    const int r = e / HHM, hh = e - r*HHM;
    cstate[(size_t)(row0 + r)*H + m*HHM + hh] = cbuf[e];
  }
}

// ---------------------------------------------------------------------------
// Head: out[b][o] = h_last[b][:] @ Wd[:,o] + bd[o]
// ---------------------------------------------------------------------------
__global__ __launch_bounds__(256) void head_kernel(
    const float* __restrict__ hlast, const float* __restrict__ Wd,
    const float* __restrict__ bd, float* __restrict__ out)
{
  const int e = blockIdx.x*256 + threadIdx.x;
  if (e >= 128*6) return;
  const int b = e / 6, o = e - 6*b;
  float s = bd[o];
  const float* hp = hlast + (size_t)b*200;
  for (int k = 0; k < 200; ++k) s += hp[k] * Wd[k*6 + o];
  out[e] = s;
}

__global__ void fill_sentinel(float* out, int n){
  const int i = blockIdx.x*blockDim.x + threadIdx.x;
  if (i < n) out[i] = 1.0e30f;   // unmistakable "workspace too small" signal
}

// ---------------------------------------------------------------------------
static constexpr int k2_lds_bytes(int H, int P){
  const int HHM = H/P, COLS = 4*HHM;
  const int CP = ((COLS+15)/16)*16;
  const int KP = ((H+31)/32)*32;
  const int KSTR = KP + 8;
  return (2*CP*KSTR + 2*16*KSTR)*2 + (16*CP + 16*COLS + 16*HHM)*4;
}

extern "C" void kernel_launch(void* const* d_in, const int* in_sizes, int n_in,
                              void* d_out, int out_size, void* d_ws, size_t ws_size,
                              hipStream_t stream)
{
  (void)in_sizes; (void)n_in;
  const float* xs  = (const float*)d_in[0];
  const float* Wx[4] = {(const float*)d_in[1], (const float*)d_in[4],
                        (const float*)d_in[7], (const float*)d_in[10]};
  const float* Wh[4] = {(const float*)d_in[2], (const float*)d_in[5],
                        (const float*)d_in[8], (const float*)d_in[11]};
  const float* bs[4] = {(const float*)d_in[3], (const float*)d_in[6],
                        (const float*)d_in[9], (const float*)d_in[12]};
  const float* Wd = (const float*)d_in[13];
  const float* bd = (const float*)d_in[14];
  float* out = (float*)d_out;

  // ---- workspace layout (fixed part) ----
  char* ws = (char*)d_ws;
  const size_t HX_BYTES = (size_t)2*8*16*224*4;        // 229376 per layer
  size_t off = 0;
  const size_t OFF_FLAGS = off; off += 4*256;                       // 4 layers
  const size_t OFF_HX    = off; off += 4*HX_BYTES;
  const size_t OFF_CST   = off; off += (size_t)4*128*200*4;
  const size_t OFF_HLAST = off; off += (size_t)128*200*4;
  off = (off + 255) & ~(size_t)255;
  const size_t FIXED_END = off;

  // ---- adaptive time-chunk: largest CT whose G+hs chunk buffers fit ----
  int CT = 0;
  for (int ct = 1024; ct >= 8; ct >>= 1){
    const size_t need = FIXED_END
                      + (size_t)ct*128*200*4      // hs chunk (max H)
                      + (size_t)ct*128*800*4;     // G chunk (max 4H)
    if (ws_size >= need){ CT = ct; break; }
  }
  if (CT == 0){
    fill_sentinel<<<(out_size + 255)/256, 256, 0, stream>>>(out, out_size);
    return;
  }
  const size_t OFF_HS = FIXED_END;
  const size_t OFF_G  = OFF_HS + (size_t)CT*128*200*4;

  unsigned* flags0 = (unsigned*)(ws + OFF_FLAGS);
  unsigned* Hx0    = (unsigned*)(ws + OFF_HX);
  float* cst       = (float*)(ws + OFF_CST);
  float* hlast     = (float*)(ws + OFF_HLAST);
  float* hs        = (float*)(ws + OFF_HS);
  float* G         = (float*)(ws + OFF_G);

  const int LDS_SMALL = k2_lds_bytes(100, 2);   // 151168
  const int LDS_BIG   = k2_lds_bytes(200, 8);   // 133952
  hipFuncSetAttribute(reinterpret_cast<const void*>(lstm_rec<100,2>),
                      hipFuncAttributeMaxDynamicSharedMemorySize, LDS_SMALL);
  hipFuncSetAttribute(reinterpret_cast<const void*>(lstm_rec<200,8>),
                      hipFuncAttributeMaxDynamicSharedMemorySize, LDS_BIG);

  // init h-state, flags (once per full forward; monotone across chunks)
  hipMemsetAsync(flags0, 0, 4*256, stream);
  hipMemsetAsync(Hx0, 0, 4*HX_BYTES, stream);

  const int NC = 1024 / CT;
  const int GMX = CT*128/256;                    // gemm grid.x per chunk
  for (int c = 0; c < NC; ++c){
    const int t0 = c*CT;
    // ---- layer 0: D=128 -> H=100 ----
    gemm_pregate<<<dim3(GMX,5), 256, 0, stream>>>(xs + (size_t)t0*128, Wx[0], bs[0], G,
        128, 4, 400, (size_t)128, (size_t)131072);          // xs[b][t][d]
    lstm_rec<100,2><<<16, 256, LDS_SMALL, stream>>>(G, Wh[0],
        Hx0 + 0*(HX_BYTES/4), flags0 + 0*64, cst + 0*(128*200),
        hs, nullptr, t0, CT, 1024);
    // ---- layer 1: 100 -> 100 ----
    gemm_pregate<<<dim3(GMX,5), 256, 0, stream>>>(hs, Wx[1], bs[1], G,
        100, 4, 400, (size_t)12800, (size_t)100);           // hs[t][b][h]
    lstm_rec<100,2><<<16, 256, LDS_SMALL, stream>>>(G, Wh[1],
        Hx0 + 1*(HX_BYTES/4), flags0 + 1*64, cst + 1*(128*200),
        hs, nullptr, t0, CT, 1024);
    // ---- layer 2: 100 -> 200 ----
    gemm_pregate<<<dim3(GMX,10), 256, 0, stream>>>(hs, Wx[2], bs[2], G,
        100, 4, 800, (size_t)12800, (size_t)100);
    lstm_rec<200,8><<<64, 256, LDS_BIG, stream>>>(G, Wh[2],
        Hx0 + 2*(HX_BYTES/4), flags0 + 2*64, cst + 2*(128*200),
        hs, nullptr, t0, CT, 1024);
    // ---- layer 3: 200 -> 200 (only last h needed) ----
    gemm_pregate<<<dim3(GMX,10), 256, 0, stream>>>(hs, Wx[3], bs[3], G,
        200, 7, 800, (size_t)25600, (size_t)200);
    lstm_rec<200,8><<<64, 256, LDS_BIG, stream>>>(G, Wh[3],
        Hx0 + 3*(HX_BYTES/4), flags0 + 3*64, cst + 3*(128*200),
        nullptr, hlast, t0, CT, 1024);
  }

  // ---- head ----
  head_kernel<<<3, 256, 0, stream>>>(hlast, Wd, bd, out);
}

// Round 3
// 14398.872 us; speedup vs baseline: 4.8631x; 4.8631x over previous
//
#include <hip/hip_runtime.h>
#include <cstdint>
#include <cstddef>

// ============================================================================
// 4-layer LSTM (B=128, T=1024, D=128, H={100,100,200,200}) + linear head.
// gemm_pregate: G = x@Wx + b (bf16x3 MFMA), time-parallel.
// lstm_rec: grouped persistent recurrence. Group = 8 blocks-sets over batch
//   (16 rows each); P members per group split the 4H gate-columns. Wh strips
//   LDS-resident (bf16 hi/lo). h exchanged via LLC: split hi/lo planes packed
//   2-per-u32, relaxed agent atomics only (no buffer_inv/wbl2 in the loop);
//   flags are relaxed, ordering via vmcnt(0)-drain at __syncthreads.
// ============================================================================

#define AGENT __HIP_MEMORY_SCOPE_AGENT

typedef __attribute__((ext_vector_type(8))) short  short8;
typedef __attribute__((ext_vector_type(4))) float  f32x4;

struct us4 { unsigned short x, y, z, w; };

__device__ __forceinline__ unsigned short f2bf(float x){
  unsigned u = __float_as_uint(x);
  unsigned r = u + 0x7FFFu + ((u >> 16) & 1u);   // RN-even to bf16
  return (unsigned short)(r >> 16);
}
__device__ __forceinline__ float bf2f(unsigned short h){
  return __uint_as_float(((unsigned)h) << 16);
}
__device__ __forceinline__ float sigmoidf_(float x){ return 1.f / (1.f + __expf(-x)); }

// ---------------------------------------------------------------------------
// K1: pregate GEMM (unchanged from R1).
// ---------------------------------------------------------------------------
__global__ __launch_bounds__(256) void gemm_pregate(
    const float* __restrict__ A, const float* __restrict__ W,
    const float* __restrict__ bias, float* __restrict__ G,
    int K, int KT, int N, size_t strideT, size_t strideB)
{
  __shared__ unsigned short Ahi[256*40];
  __shared__ unsigned short Alo[256*40];
  __shared__ unsigned short Bhi[80*40];
  __shared__ unsigned short Blo[80*40];

  const int tid  = threadIdx.x;
  const int mb   = blockIdx.x;
  const int n0   = blockIdx.y * 80;
  const int wave = tid >> 6, lane = tid & 63;
  const int ln15 = lane & 15, quad = lane >> 4;

  f32x4 acc[4][5];
  for (int a = 0; a < 4; ++a)
    for (int b = 0; b < 5; ++b)
      acc[a][b] = (f32x4){0.f, 0.f, 0.f, 0.f};

  for (int kt = 0; kt < KT; ++kt){
    const int k0 = kt * 32;
    const bool full = (k0 + 31) < K;
    for (int i = 0; i < 8; ++i){
      const int e   = tid + 256*i;
      const int row = e >> 3, seg = e & 7;
      const int mm  = mb*256 + row;
      const float* rp = A + (size_t)(mm >> 7)*strideT + (size_t)(mm & 127)*strideB;
      const int k = k0 + seg*4;
      float v0, v1, v2, v3;
      if (full){
        float4 v = *(const float4*)(rp + k);
        v0 = v.x; v1 = v.y; v2 = v.z; v3 = v.w;
      } else {
        v0 = (k+0 < K) ? rp[k+0] : 0.f;
        v1 = (k+1 < K) ? rp[k+1] : 0.f;
        v2 = (k+2 < K) ? rp[k+2] : 0.f;
        v3 = (k+3 < K) ? rp[k+3] : 0.f;
      }
      const unsigned short h0=f2bf(v0), h1=f2bf(v1), h2=f2bf(v2), h3=f2bf(v3);
      us4 hv{h0, h1, h2, h3};
      us4 lv{f2bf(v0-bf2f(h0)), f2bf(v1-bf2f(h1)), f2bf(v2-bf2f(h2)), f2bf(v3-bf2f(h3))};
      *(us4*)&Ahi[row*40 + seg*4] = hv;
      *(us4*)&Alo[row*40 + seg*4] = lv;
    }
    for (int i = 0; i < 10; ++i){
      const int e  = tid + 256*i;
      const int kk = e / 80, nn = e - kk*80;
      const int k  = k0 + kk;
      const float v = (k < K) ? W[(size_t)k*N + n0 + nn] : 0.f;
      const unsigned short hb = f2bf(v);
      Bhi[nn*40 + kk] = hb;
      Blo[nn*40 + kk] = f2bf(v - bf2f(hb));
    }
    __syncthreads();
    short8 a_h[4], a_l[4];
    for (int mt = 0; mt < 4; ++mt){
      const int aoff = (wave*64 + mt*16 + ln15)*40 + quad*8;
      a_h[mt] = *(const short8*)&Ahi[aoff];
      a_l[mt] = *(const short8*)&Alo[aoff];
    }
    for (int nt = 0; nt < 5; ++nt){
      const int boff = (nt*16 + ln15)*40 + quad*8;
      const short8 b_h = *(const short8*)&Bhi[boff];
      const short8 b_l = *(const short8*)&Blo[boff];
      for (int mt = 0; mt < 4; ++mt){
        acc[mt][nt] = __builtin_amdgcn_mfma_f32_16x16x32_bf16(a_h[mt], b_h, acc[mt][nt], 0,0,0);
        acc[mt][nt] = __builtin_amdgcn_mfma_f32_16x16x32_bf16(a_l[mt], b_h, acc[mt][nt], 0,0,0);
        acc[mt][nt] = __builtin_amdgcn_mfma_f32_16x16x32_bf16(a_h[mt], b_l, acc[mt][nt], 0,0,0);
      }
    }
    __syncthreads();
  }
  for (int nt = 0; nt < 5; ++nt){
    const float bv = bias[n0 + nt*16 + ln15];
    for (int mt = 0; mt < 4; ++mt){
      const int mbase = mb*256 + wave*64 + mt*16 + quad*4;
      #pragma unroll
      for (int r = 0; r < 4; ++r)
        G[(size_t)(mbase + r)*N + n0 + nt*16 + ln15] = acc[mt][nt][r] + bv;
    }
  }
}

// ---------------------------------------------------------------------------
// K2 v2: group = 8 (batch tiles of 16), member m of P owns HHM=H/P hidden
// units across all 4 gates (COLS=4*HHM columns). Requirements: HHM even.
// Hx layout per (parity,g): [plane(hi/lo)][16 rows][112 u32] ; u32 packs
// k (low16) and k+1 (high16). Flags: 16 u32 per group per layer.
// Per step: 3 barriers, relaxed atomics only, A-frags loaded straight
// from LLC as u64 pairs, c-state in registers.
// ---------------------------------------------------------------------------
template<int H, int P>
__global__ __launch_bounds__(256) void lstm_rec(
    const float* __restrict__ G, const float* __restrict__ Wh,
    unsigned* __restrict__ Hx, unsigned* __restrict__ flags,
    float* __restrict__ cstate, float* __restrict__ hseq_out,
    float* __restrict__ hlast, int t0, int TC, int Tlast)
{
  constexpr int HHM  = H / P;               // hidden units per member (even)
  static_assert((HHM & 1) == 0, "HHM must be even");
  constexpr int COLS = 4 * HHM;
  constexpr int CP   = ((COLS + 15)/16)*16;
  constexpr int KP   = ((H + 31)/32)*32;
  constexpr int KSTR = KP + 8;
  constexpr int NT   = CP / 16;
  constexpr int KT   = KP / 32;
  constexpr int N4H  = 4 * H;
  constexpr int MAXNT = (NT + 3) / 4;
  constexpr int NE   = 16 * HHM / 2;        // u32-pairs handled in gate stage
  constexpr int PR   = HHM / 2;             // pairs per row

  extern __shared__ char smem[];
  unsigned short* whT_hi = (unsigned short*)smem;
  unsigned short* whT_lo = whT_hi + CP*KSTR;
  float* zbuf = (float*)(whT_lo + CP*KSTR);   // [16][CP]

  const int tid  = threadIdx.x;
  const int g    = blockIdx.x & 7;
  const int m    = blockIdx.x >> 3;
  const int row0 = g * 16;
  const int lane = tid & 63;
  const int wave = tid >> 6;
  const int ln15 = lane & 15, quad = lane >> 4;

  for (int e = tid; e < CP*KSTR; e += 256){ whT_hi[e] = 0; whT_lo[e] = 0; }
  __syncthreads();
  // load member's Wh strip, [col][k], hi/lo bf16
  for (int e = tid; e < H*COLS; e += 256){
    const int k = e / COLS, c = e - k*COLS;
    const int gate = c / HHM, hh = c - gate*HHM;
    const float w = Wh[(size_t)k*N4H + gate*H + m*HHM + hh];
    const unsigned short hi = f2bf(w);
    whT_hi[c*KSTR + k] = hi;
    whT_lo[c*KSTR + k] = f2bf(w - bf2f(hi));
  }

  // gate-stage thread coords + persistent c in registers
  const int r_g  = tid / PR;               // row (valid if tid < NE)
  const int pi_g = tid - r_g*PR;
  const int hh0  = 2*pi_g;                 // member-local hidden pair
  const int kidx = m*HHM + hh0;            // global hidden index (even)
  float c0 = 0.f, c1 = 0.f;
  if (tid < NE && t0 > 0){
    const float2 cv = *(const float2*)&cstate[(size_t)(row0 + r_g)*H + kidx];
    c0 = cv.x; c1 = cv.y;
  }
  __syncthreads();

  unsigned* flg = flags + g*16;

  for (int tl = 0; tl < TC; ++tl){
    const int t = t0 + tl;

    // G for this thread's pair: 4 gates x float2 (independent of h)
    float2 gv[4];
    if (tid < NE){
      const float* Gt = G + ((size_t)tl*128 + row0 + r_g)*N4H + m*HHM + hh0;
      #pragma unroll
      for (int gate = 0; gate < 4; ++gate)
        gv[gate] = *(const float2*)(Gt + gate*H);
    }

    // wait for all P members' h_t (parallel per-lane relaxed polls)
    if (t > 0 && tid < P){
      long spins = 0;
      while (__hip_atomic_load(&flg[tid], __ATOMIC_RELAXED, AGENT) < (unsigned)t){
        if (++spins > (1L << 24)) break;   // safety valve
      }
    }
    __syncthreads();

    // A fragments straight from LLC: row=ln15, k=kt*32+quad*8..+7
    const unsigned* hx = Hx + (size_t)((t & 1)*8 + g) * 3584;
    union U { unsigned long long q[2]; short8 v; };
    short8 a_h[KT], a_l[KT];
    #pragma unroll
    for (int kt = 0; kt < KT; ++kt){
      const int w32 = ln15*112 + kt*16 + quad*4;
      const unsigned long long* ph = (const unsigned long long*)&hx[w32];
      const unsigned long long* pl = (const unsigned long long*)&hx[1792 + w32];
      U uh, ul;
      uh.q[0] = __hip_atomic_load(ph+0, __ATOMIC_RELAXED, AGENT);
      uh.q[1] = __hip_atomic_load(ph+1, __ATOMIC_RELAXED, AGENT);
      ul.q[0] = __hip_atomic_load(pl+0, __ATOMIC_RELAXED, AGENT);
      ul.q[1] = __hip_atomic_load(pl+1, __ATOMIC_RELAXED, AGENT);
      a_h[kt] = uh.v; a_l[kt] = ul.v;
    }

    // z = h_t @ Wh_strip (bf16x3), nt round-robin over 4 waves
    f32x4 acc[MAXNT];
    #pragma unroll
    for (int i = 0; i < MAXNT; ++i) acc[i] = (f32x4){0.f,0.f,0.f,0.f};
    #pragma unroll
    for (int kt = 0; kt < KT; ++kt){
      const int ko = kt*32;
      int ntl = 0;
      for (int nt = wave; nt < NT; nt += 4, ++ntl){
        const int boff = (nt*16 + ln15)*KSTR + quad*8 + ko;
        const short8 b_h = *(const short8*)&whT_hi[boff];
        const short8 b_l = *(const short8*)&whT_lo[boff];
        acc[ntl] = __builtin_amdgcn_mfma_f32_16x16x32_bf16(a_h[kt], b_h, acc[ntl], 0,0,0);
        acc[ntl] = __builtin_amdgcn_mfma_f32_16x16x32_bf16(a_l[kt], b_h, acc[ntl], 0,0,0);
        acc[ntl] = __builtin_amdgcn_mfma_f32_16x16x32_bf16(a_h[kt], b_l, acc[ntl], 0,0,0);
      }
    }
    {
      int ntl = 0;
      for (int nt = wave; nt < NT; nt += 4, ++ntl)
        #pragma unroll
        for (int r = 0; r < 4; ++r)
          zbuf[(quad*4 + r)*CP + nt*16 + ln15] = acc[ntl][r];
    }
    __syncthreads();

    // gates + state update + publish (relaxed agent atomics)
    if (tid < NE){
      const float* zr = zbuf + r_g*CP;
      const float zi0 = zr[0*HHM + hh0]     + gv[0].x;
      const float zi1 = zr[0*HHM + hh0 + 1] + gv[0].y;
      const float zf0 = zr[1*HHM + hh0]     + gv[1].x;
      const float zf1 = zr[1*HHM + hh0 + 1] + gv[1].y;
      const float zg0 = zr[2*HHM + hh0]     + gv[2].x;
      const float zg1 = zr[2*HHM + hh0 + 1] + gv[2].y;
      const float zo0 = zr[3*HHM + hh0]     + gv[3].x;
      const float zo1 = zr[3*HHM + hh0 + 1] + gv[3].y;
      c0 = sigmoidf_(zf0)*c0 + sigmoidf_(zi0)*tanhf(zg0);
      c1 = sigmoidf_(zf1)*c1 + sigmoidf_(zi1)*tanhf(zg1);
      const float h0 = sigmoidf_(zo0)*tanhf(c0);
      const float h1 = sigmoidf_(zo1)*tanhf(c1);
      const unsigned short h0h = f2bf(h0), h1h = f2bf(h1);
      const unsigned short h0l = f2bf(h0 - bf2f(h0h)), h1l = f2bf(h1 - bf2f(h1h));
      const unsigned whi = ((unsigned)h1h << 16) | (unsigned)h0h;
      const unsigned wlo = ((unsigned)h1l << 16) | (unsigned)h0l;
      unsigned* dst = Hx + (size_t)(((t+1) & 1)*8 + g) * 3584;
      const int w32 = r_g*112 + kidx/2;
      __hip_atomic_store(&dst[w32],        whi, __ATOMIC_RELAXED, AGENT);
      __hip_atomic_store(&dst[1792 + w32], wlo, __ATOMIC_RELAXED, AGENT);
      if (hseq_out){
        float2 hv{h0, h1};
        *(float2*)&hseq_out[((size_t)tl*128 + row0 + r_g)*(size_t)H + kidx] = hv;
      }
      if (hlast && t == Tlast-1){
        float2 hv{h0, h1};
        *(float2*)&hlast[(size_t)(row0 + r_g)*H + kidx] = hv;
      }
    }
    __syncthreads();   // vmcnt(0)-drain before barrier => h stores LLC-visible
    if (tid == 0)
      __hip_atomic_store(&flg[m], (unsigned)(t+1), __ATOMIC_RELAXED, AGENT);
  }

  // persist c-state for next chunk
  if (tid < NE){
    float2 cv{c0, c1};
    *(float2*)&cstate[(size_t)(row0 + r_g)*H + kidx] = cv;
  }
}

// ---------------------------------------------------------------------------
__global__ __launch_bounds__(256) void head_kernel(
    const float* __restrict__ hlast, const float* __restrict__ Wd,
    const float* __restrict__ bd, float* __restrict__ out)
{
  const int e = blockIdx.x*256 + threadIdx.x;
  if (e >= 128*6) return;
  const int b = e / 6, o = e - 6*b;
  float s = bd[o];
  const float* hp = hlast + (size_t)b*200;
  for (int k = 0; k < 200; ++k) s += hp[k] * Wd[k*6 + o];
  out[e] = s;
}

__global__ void fill_sentinel(float* out, int n){
  const int i = blockIdx.x*blockDim.x + threadIdx.x;
  if (i < n) out[i] = 1.0e30f;
}

// ---------------------------------------------------------------------------
static constexpr int k2_lds_bytes(int H, int P){
  const int HHM = H/P, COLS = 4*HHM;
  const int CP = ((COLS+15)/16)*16;
  const int KP = ((H+31)/32)*32;
  const int KSTR = KP + 8;
  return 4*CP*KSTR + 16*CP*4;   // 2 short planes + zbuf
}

extern "C" void kernel_launch(void* const* d_in, const int* in_sizes, int n_in,
                              void* d_out, int out_size, void* d_ws, size_t ws_size,
                              hipStream_t stream)
{
  (void)in_sizes; (void)n_in;
  const float* xs  = (const float*)d_in[0];
  const float* Wx[4] = {(const float*)d_in[1], (const float*)d_in[4],
                        (const float*)d_in[7], (const float*)d_in[10]};
  const float* Wh[4] = {(const float*)d_in[2], (const float*)d_in[5],
                        (const float*)d_in[8], (const float*)d_in[11]};
  const float* bs[4] = {(const float*)d_in[3], (const float*)d_in[6],
                        (const float*)d_in[9], (const float*)d_in[12]};
  const float* Wd = (const float*)d_in[13];
  const float* bd = (const float*)d_in[14];
  float* out = (float*)d_out;

  // ---- workspace layout ----
  char* ws = (char*)d_ws;
  const size_t HX_U32  = (size_t)2*8*2*16*112;          // per layer (u32s)
  const size_t HX_BYTES = HX_U32*4;                      // 229376
  size_t off = 0;
  const size_t OFF_FLAGS = off; off += (size_t)4*8*16*4; // 4 layers x 8 grp x 16
  const size_t OFF_HX    = off; off += 4*HX_BYTES;
  const size_t OFF_CST   = off; off += (size_t)4*128*200*4;
  const size_t OFF_HLAST = off; off += (size_t)128*200*4;
  off = (off + 255) & ~(size_t)255;
  const size_t FIXED_END = off;

  int CT = 0;
  for (int ct = 1024; ct >= 8; ct >>= 1){
    const size_t need = FIXED_END
                      + (size_t)ct*128*200*4
                      + (size_t)ct*128*800*4;
    if (ws_size >= need){ CT = ct; break; }
  }
  if (CT == 0){
    fill_sentinel<<<(out_size + 255)/256, 256, 0, stream>>>(out, out_size);
    return;
  }
  const size_t OFF_HS = FIXED_END;
  const size_t OFF_G  = OFF_HS + (size_t)CT*128*200*4;

  unsigned* flags0 = (unsigned*)(ws + OFF_FLAGS);
  unsigned* Hx0    = (unsigned*)(ws + OFF_HX);
  float* cst       = (float*)(ws + OFF_CST);
  float* hlast     = (float*)(ws + OFF_HLAST);
  float* hs        = (float*)(ws + OFF_HS);
  float* G         = (float*)(ws + OFF_G);

  const int LDS_SMALL = k2_lds_bytes(100, 5);   // 48640
  const int LDS_BIG   = k2_lds_bytes(200, 10);  // 79360
  hipFuncSetAttribute(reinterpret_cast<const void*>(lstm_rec<100,5>),
                      hipFuncAttributeMaxDynamicSharedMemorySize, LDS_SMALL);
  hipFuncSetAttribute(reinterpret_cast<const void*>(lstm_rec<200,10>),
                      hipFuncAttributeMaxDynamicSharedMemorySize, LDS_BIG);

  hipMemsetAsync(flags0, 0, 4*8*16*4, stream);
  hipMemsetAsync(Hx0, 0, 4*HX_BYTES, stream);

  const int NC = 1024 / CT;
  const int GMX = CT*128/256;
  for (int c = 0; c < NC; ++c){
    const int t0 = c*CT;
    // layer 0: D=128 -> H=100
    gemm_pregate<<<dim3(GMX,5), 256, 0, stream>>>(xs + (size_t)t0*128, Wx[0], bs[0], G,
        128, 4, 400, (size_t)128, (size_t)131072);
    lstm_rec<100,5><<<40, 256, LDS_SMALL, stream>>>(G, Wh[0],
        Hx0 + 0*HX_U32, flags0 + 0*128, cst + 0*(128*200),
        hs, nullptr, t0, CT, 1024);
    // layer 1: 100 -> 100
    gemm_pregate<<<dim3(GMX,5), 256, 0, stream>>>(hs, Wx[1], bs[1], G,
        100, 4, 400, (size_t)12800, (size_t)100);
    lstm_rec<100,5><<<40, 256, LDS_SMALL, stream>>>(G, Wh[1],
        Hx0 + 1*HX_U32, flags0 + 1*128, cst + 1*(128*200),
        hs, nullptr, t0, CT, 1024);
    // layer 2: 100 -> 200
    gemm_pregate<<<dim3(GMX,10), 256, 0, stream>>>(hs, Wx[2], bs[2], G,
        100, 4, 800, (size_t)12800, (size_t)100);
    lstm_rec<200,10><<<80, 256, LDS_BIG, stream>>>(G, Wh[2],
        Hx0 + 2*HX_U32, flags0 + 2*128, cst + 2*(128*200),
        hs, nullptr, t0, CT, 1024);
    // layer 3: 200 -> 200
    gemm_pregate<<<dim3(GMX,10), 256, 0, stream>>>(hs, Wx[3], bs[3], G,
        200, 7, 800, (size_t)25600, (size_t)200);
    lstm_rec<200,10><<<80, 256, LDS_BIG, stream>>>(G, Wh[3],
        Hx0 + 3*HX_U32, flags0 + 3*128, cst + 3*(128*200),
        nullptr, hlast, t0, CT, 1024);
  }

  head_kernel<<<3, 256, 0, stream>>>(hlast, Wd, bd, out);
}

// Round 4
// 8681.751 us; speedup vs baseline: 8.0656x; 1.6585x over previous
//
#include <hip/hip_runtime.h>
#include <cstdint>
#include <cstddef>

// ============================================================================
// 4-layer LSTM (B=128, T=1024, D=128, H={100,100,200,200}) + linear head.
// R4: single fused persistent pipeline kernel. All 4 layers run concurrently,
// skewed by one timestep (layer L step t needs layer L-1 step t). Layers 1-3
// fold x@Wx into the recurrent MFMA via K-concatenation [x_t ; h_{t-1}].
// Only layer 0 keeps a separate pregate GEMM (xs known upfront).
// h exchange via LLC: packed bf16 hi/lo planes, relaxed agent atomics,
// per-member monotonic flags; parity-2 slots with downstream backpressure.
// ============================================================================

#define AGENT __HIP_MEMORY_SCOPE_AGENT

typedef __attribute__((ext_vector_type(8))) short  short8;
typedef __attribute__((ext_vector_type(4))) float  f32x4;

struct us4 { unsigned short x, y, z, w; };

__device__ __forceinline__ unsigned short f2bf(float x){
  unsigned u = __float_as_uint(x);
  unsigned r = u + 0x7FFFu + ((u >> 16) & 1u);   // RN-even to bf16
  return (unsigned short)(r >> 16);
}
__device__ __forceinline__ float bf2f(unsigned short h){
  return __uint_as_float(((unsigned)h) << 16);
}
__device__ __forceinline__ float sigmoidf_(float x){ return 1.f / (1.f + __expf(-x)); }

__device__ __forceinline__ void spin_ge(const unsigned* p, unsigned v){
  long s = 0;
  while (__hip_atomic_load(p, __ATOMIC_RELAXED, AGENT) < v){
    if (++s > (1L << 24)) break;   // safety valve
  }
}

__device__ __forceinline__ void load_hx(const unsigned* base, int w32, int loOff,
                                        short8& ah, short8& al){
  union U { unsigned long long q[2]; short8 v; } uh, ul;
  const unsigned long long* ph = (const unsigned long long*)(base + w32);
  const unsigned long long* pl = (const unsigned long long*)(base + loOff + w32);
  uh.q[0] = __hip_atomic_load(ph + 0, __ATOMIC_RELAXED, AGENT);
  uh.q[1] = __hip_atomic_load(ph + 1, __ATOMIC_RELAXED, AGENT);
  ul.q[0] = __hip_atomic_load(pl + 0, __ATOMIC_RELAXED, AGENT);
  ul.q[1] = __hip_atomic_load(pl + 1, __ATOMIC_RELAXED, AGENT);
  ah = uh.v; al = ul.v;
}

// ---------------------------------------------------------------------------
// K1: pregate GEMM for layer 0 only.  G[m][n] = xs_row(m) @ Wx0 + b0.
// ---------------------------------------------------------------------------
__global__ __launch_bounds__(256) void gemm_pregate(
    const float* __restrict__ A, const float* __restrict__ W,
    const float* __restrict__ bias, float* __restrict__ G,
    int K, int KT, int N, size_t strideT, size_t strideB)
{
  __shared__ unsigned short Ahi[256*40];
  __shared__ unsigned short Alo[256*40];
  __shared__ unsigned short Bhi[80*40];
  __shared__ unsigned short Blo[80*40];

  const int tid  = threadIdx.x;
  const int mb   = blockIdx.x;
  const int n0   = blockIdx.y * 80;
  const int wave = tid >> 6, lane = tid & 63;
  const int ln15 = lane & 15, quad = lane >> 4;

  f32x4 acc[4][5];
  for (int a = 0; a < 4; ++a)
    for (int b = 0; b < 5; ++b)
      acc[a][b] = (f32x4){0.f, 0.f, 0.f, 0.f};

  for (int kt = 0; kt < KT; ++kt){
    const int k0 = kt * 32;
    const bool full = (k0 + 31) < K;
    for (int i = 0; i < 8; ++i){
      const int e   = tid + 256*i;
      const int row = e >> 3, seg = e & 7;
      const int mm  = mb*256 + row;
      const float* rp = A + (size_t)(mm >> 7)*strideT + (size_t)(mm & 127)*strideB;
      const int k = k0 + seg*4;
      float v0, v1, v2, v3;
      if (full){
        float4 v = *(const float4*)(rp + k);
        v0 = v.x; v1 = v.y; v2 = v.z; v3 = v.w;
      } else {
        v0 = (k+0 < K) ? rp[k+0] : 0.f;
        v1 = (k+1 < K) ? rp[k+1] : 0.f;
        v2 = (k+2 < K) ? rp[k+2] : 0.f;
        v3 = (k+3 < K) ? rp[k+3] : 0.f;
      }
      const unsigned short h0=f2bf(v0), h1=f2bf(v1), h2=f2bf(v2), h3=f2bf(v3);
      us4 hv{h0, h1, h2, h3};
      us4 lv{f2bf(v0-bf2f(h0)), f2bf(v1-bf2f(h1)), f2bf(v2-bf2f(h2)), f2bf(v3-bf2f(h3))};
      *(us4*)&Ahi[row*40 + seg*4] = hv;
      *(us4*)&Alo[row*40 + seg*4] = lv;
    }
    for (int i = 0; i < 10; ++i){
      const int e  = tid + 256*i;
      const int kk = e / 80, nn = e - kk*80;
      const int k  = k0 + kk;
      const float v = (k < K) ? W[(size_t)k*N + n0 + nn] : 0.f;
      const unsigned short hb = f2bf(v);
      Bhi[nn*40 + kk] = hb;
      Blo[nn*40 + kk] = f2bf(v - bf2f(hb));
    }
    __syncthreads();
    short8 a_h[4], a_l[4];
    for (int mt = 0; mt < 4; ++mt){
      const int aoff = (wave*64 + mt*16 + ln15)*40 + quad*8;
      a_h[mt] = *(const short8*)&Ahi[aoff];
      a_l[mt] = *(const short8*)&Alo[aoff];
    }
    for (int nt = 0; nt < 5; ++nt){
      const int boff = (nt*16 + ln15)*40 + quad*8;
      const short8 b_h = *(const short8*)&Bhi[boff];
      const short8 b_l = *(const short8*)&Blo[boff];
      for (int mt = 0; mt < 4; ++mt){
        acc[mt][nt] = __builtin_amdgcn_mfma_f32_16x16x32_bf16(a_h[mt], b_h, acc[mt][nt], 0,0,0);
        acc[mt][nt] = __builtin_amdgcn_mfma_f32_16x16x32_bf16(a_l[mt], b_h, acc[mt][nt], 0,0,0);
        acc[mt][nt] = __builtin_amdgcn_mfma_f32_16x16x32_bf16(a_h[mt], b_l, acc[mt][nt], 0,0,0);
      }
    }
    __syncthreads();
  }
  for (int nt = 0; nt < 5; ++nt){
    const float bv = bias[n0 + nt*16 + ln15];
    for (int mt = 0; mt < 4; ++mt){
      const int mbase = mb*256 + wave*64 + mt*16 + quad*4;
      #pragma unroll
      for (int r = 0; r < 4; ++r)
        G[(size_t)(mbase + r)*N + n0 + nt*16 + ln15] = acc[mt][nt][r] + bv;
    }
  }
}

// ---------------------------------------------------------------------------
// Fused pipeline stage. Template: H (own hidden), HP (padded upstream width,
// 0 if no x-part), P (members per group), HAS_X.
// Group g owns batch rows [16g,16g+16); member m owns HHM=H/P hidden units
// across all 4 gates (COLS=4*HHM=80 weight columns).
// Hx layout per (parity,g): [plane hi/lo][16 rows][RS u32], u32 packs 2 bf16.
// ---------------------------------------------------------------------------
template<int H, int HP, int P, bool HAS_X>
__device__ __forceinline__ void rec_stage(
    const float* __restrict__ G0, const float* __restrict__ Wx,
    const float* __restrict__ Wh, const float* __restrict__ bias,
    int HprevReal,
    const unsigned* __restrict__ HxUp, unsigned* __restrict__ HxOwn,
    const unsigned* __restrict__ flgUp, unsigned* __restrict__ flgOwn,
    unsigned* __restrict__ flgDn, int PUp, int PDn,
    float* __restrict__ cstate, float* __restrict__ hlast,
    int g, int m, int t0, int TC, int Tlast, char* smem)
{
  constexpr int HHM  = H / P;                 // 20
  constexpr int COLS = 4 * HHM;               // 80
  constexpr int CP   = COLS;                  // multiple of 16
  constexpr int KPo  = ((H + 31)/32)*32;      // own-h padded K
  constexpr int RSo  = KPo / 2;               // own Hx row stride (u32)
  constexpr int RSp  = HP / 2;                // upstream Hx row stride
  constexpr int KX   = HAS_X ? HP : 0;
  constexpr int KALL = KX + KPo;
  constexpr int KTX  = KX / 32;
  constexpr int KTH  = KPo / 32;
  constexpr int KSTR = KALL + 8;
  constexpr int NT   = CP / 16;               // 5
  constexpr int NE   = 16 * HHM / 2;          // 160
  constexpr int PR   = HHM / 2;               // 10
  constexpr int N4H  = 4 * H;

  unsigned short* whT_hi = (unsigned short*)smem;
  unsigned short* whT_lo = whT_hi + CP*KSTR;
  float* zbuf = (float*)(whT_lo + CP*KSTR);   // [16][CP]

  const int tid  = threadIdx.x;
  const int row0 = g * 16;
  const int lane = tid & 63, wave = tid >> 6;
  const int ln15 = lane & 15, quad = lane >> 4;

  // stage concatenated weight strip [col][k], hi/lo bf16 (zeros in pad rows)
  for (int e = tid; e < COLS*KALL; e += 256){
    const int k = e / COLS, c = e - k*COLS;
    const int gate = c / HHM, hh = c - gate*HHM;
    const int col = gate*H + m*HHM + hh;
    float w = 0.f;
    if (HAS_X){
      if (k < KX){ if (k < HprevReal) w = Wx[(size_t)k*N4H + col]; }
      else { const int k2 = k - KX; if (k2 < H) w = Wh[(size_t)k2*N4H + col]; }
    } else {
      if (k < H) w = Wh[(size_t)k*N4H + col];
    }
    const unsigned short hi = f2bf(w);
    whT_hi[c*KSTR + k] = hi;
    whT_lo[c*KSTR + k] = f2bf(w - bf2f(hi));
  }

  const int r_g  = tid / PR;
  const int hh0  = 2*(tid - r_g*PR);
  const int kidx = m*HHM + hh0;
  float c0 = 0.f, c1 = 0.f;
  if (tid < NE && t0 > 0){
    const float2 cv = *(const float2*)&cstate[(size_t)(row0 + r_g)*H + kidx];
    c0 = cv.x; c1 = cv.y;
  }
  float2 bv[4] = {};
  if (HAS_X){
    if (tid < NE){
      #pragma unroll
      for (int gate = 0; gate < 4; ++gate)
        bv[gate] = *(const float2*)&bias[gate*H + kidx];
    }
  }
  __syncthreads();

  const int g16 = g*16;

  for (int tl = 0; tl < TC; ++tl){
    const int t = t0 + tl;

    // layer-0 pregate values (independent of h; overlaps the flag waits)
    float2 gv[4] = {};
    if constexpr (!HAS_X){
      if (tid < NE){
        const float* Gt = G0 + ((size_t)tl*128 + row0 + r_g)*(size_t)N4H + kidx;
        #pragma unroll
        for (int gate = 0; gate < 4; ++gate)
          gv[gate] = *(const float2*)(Gt + gate*H);
      }
    }

    // waits: own >= t, upstream >= t+1, downstream >= t-1
    if (tid < P) spin_ge(&flgOwn[g16 + tid], (unsigned)t);
    else if (HAS_X && tid >= 16 && tid < 16 + PUp)
      spin_ge(&flgUp[g16 + tid - 16], (unsigned)(t+1));
    else if (PDn > 0 && t > 0 && tid >= 32 && tid < 32 + PDn)
      spin_ge(&flgDn[g16 + tid - 32], (unsigned)(t-1));
    __syncthreads();

    // z = [x_t ; h_{t-1}] @ Wcat  (bf16x3)
    f32x4 acc[2];
    acc[0] = (f32x4){0.f,0.f,0.f,0.f};
    acc[1] = (f32x4){0.f,0.f,0.f,0.f};
    auto do_tile = [&](const short8& a_h, const short8& a_l, int koW){
      #pragma unroll
      for (int s = 0; s < 2; ++s){
        const int nt = wave + 4*s;
        if (nt < NT){
          const int boff = (nt*16 + ln15)*KSTR + quad*8 + koW;
          const short8 b_h = *(const short8*)&whT_hi[boff];
          const short8 b_l = *(const short8*)&whT_lo[boff];
          acc[s] = __builtin_amdgcn_mfma_f32_16x16x32_bf16(a_h, b_h, acc[s], 0,0,0);
          acc[s] = __builtin_amdgcn_mfma_f32_16x16x32_bf16(a_l, b_h, acc[s], 0,0,0);
          acc[s] = __builtin_amdgcn_mfma_f32_16x16x32_bf16(a_h, b_l, acc[s], 0,0,0);
        }
      }
    };
    if constexpr (HAS_X){
      const unsigned* up = HxUp + (size_t)(((t+1)&1)*8 + g) * (2*16*RSp);
      #pragma unroll
      for (int kt = 0; kt < KTX; ++kt){
        short8 a_h, a_l;
        load_hx(up, ln15*RSp + kt*16 + quad*4, 16*RSp, a_h, a_l);
        do_tile(a_h, a_l, kt*32);
      }
    }
    {
      const unsigned* own = HxOwn + (size_t)((t&1)*8 + g) * (2*16*RSo);
      #pragma unroll
      for (int kt = 0; kt < KTH; ++kt){
        short8 a_h, a_l;
        load_hx(own, ln15*RSo + kt*16 + quad*4, 16*RSo, a_h, a_l);
        do_tile(a_h, a_l, KX + kt*32);
      }
    }
    {
      #pragma unroll
      for (int s = 0; s < 2; ++s){
        const int nt = wave + 4*s;
        if (nt < NT)
          #pragma unroll
          for (int r = 0; r < 4; ++r)
            zbuf[(quad*4 + r)*CP + nt*16 + ln15] = acc[s][r];
      }
    }
    __syncthreads();

    // gates + state update + publish
    if (tid < NE){
      const float* zr = zbuf + r_g*CP;
      float zi0, zi1, zf0, zf1, zg0, zg1, zo0, zo1;
      {
        const float2 b0 = HAS_X ? bv[0] : gv[0];
        const float2 b1 = HAS_X ? bv[1] : gv[1];
        const float2 b2 = HAS_X ? bv[2] : gv[2];
        const float2 b3 = HAS_X ? bv[3] : gv[3];
        zi0 = zr[0*HHM + hh0]   + b0.x;  zi1 = zr[0*HHM + hh0+1] + b0.y;
        zf0 = zr[1*HHM + hh0]   + b1.x;  zf1 = zr[1*HHM + hh0+1] + b1.y;
        zg0 = zr[2*HHM + hh0]   + b2.x;  zg1 = zr[2*HHM + hh0+1] + b2.y;
        zo0 = zr[3*HHM + hh0]   + b3.x;  zo1 = zr[3*HHM + hh0+1] + b3.y;
      }
      c0 = sigmoidf_(zf0)*c0 + sigmoidf_(zi0)*tanhf(zg0);
      c1 = sigmoidf_(zf1)*c1 + sigmoidf_(zi1)*tanhf(zg1);
      const float h0 = sigmoidf_(zo0)*tanhf(c0);
      const float h1 = sigmoidf_(zo1)*tanhf(c1);
      const unsigned short h0h = f2bf(h0), h1h = f2bf(h1);
      const unsigned short h0l = f2bf(h0 - bf2f(h0h)), h1l = f2bf(h1 - bf2f(h1h));
      const unsigned whi = ((unsigned)h1h << 16) | (unsigned)h0h;
      const unsigned wlo = ((unsigned)h1l << 16) | (unsigned)h0l;
      unsigned* dst = HxOwn + (size_t)(((t+1)&1)*8 + g) * (2*16*RSo);
      const int w32 = r_g*RSo + (kidx >> 1);
      __hip_atomic_store(&dst[w32],            whi, __ATOMIC_RELAXED, AGENT);
      __hip_atomic_store(&dst[16*RSo + w32],   wlo, __ATOMIC_RELAXED, AGENT);
      if (hlast && t == Tlast-1){
        float2 hv{h0, h1};
        *(float2*)&hlast[(size_t)(row0 + r_g)*H + kidx] = hv;
      }
    }
    __syncthreads();   // vmcnt(0)-drain per wave => h stores LLC-visible
    if (tid == 0)
      __hip_atomic_store(&flgOwn[g16 + m], (unsigned)(t+1), __ATOMIC_RELAXED, AGENT);
  }

  // persist c-state for the next chunk
  if (tid < NE){
    float2 cv{c0, c1};
    *(float2*)&cstate[(size_t)(row0 + r_g)*H + kidx] = cv;
  }
}

struct FusedArgs {
  const float *G0;
  const float *Wx1, *Wx2, *Wx3;
  const float *Wh0, *Wh1, *Wh2, *Wh3;
  const float *b1, *b2, *b3;
  unsigned *Hx0, *Hx1, *Hx2, *Hx3;
  unsigned *flags;                 // 4 layers x 128 u32
  float *cst;                      // 4 x 128 x 200
  float *hlast;
  int t0, TC, Tlast;
};

// Blocks: [0,40)=L0, [40,80)=L1, [80,160)=L2, [160,240)=L3.
__global__ __launch_bounds__(256) void lstm_fused(FusedArgs a){
  extern __shared__ char smem[];
  const int b = blockIdx.x;
  if (b < 40){
    rec_stage<100, 0, 5, false>(a.G0, nullptr, a.Wh0, nullptr, 0,
        nullptr, a.Hx0, nullptr, a.flags + 0, a.flags + 128, 0, 5,
        a.cst + 0*128*200, nullptr, b & 7, b >> 3, a.t0, a.TC, a.Tlast, smem);
  } else if (b < 80){
    const int bb = b - 40;
    rec_stage<100, 128, 5, true>(nullptr, a.Wx1, a.Wh1, a.b1, 100,
        a.Hx0, a.Hx1, a.flags + 0, a.flags + 128, a.flags + 256, 5, 10,
        a.cst + 1*128*200, nullptr, bb & 7, bb >> 3, a.t0, a.TC, a.Tlast, smem);
  } else if (b < 160){
    const int bb = b - 80;
    rec_stage<200, 128, 10, true>(nullptr, a.Wx2, a.Wh2, a.b2, 100,
        a.Hx1, a.Hx2, a.flags + 128, a.flags + 256, a.flags + 384, 5, 10,
        a.cst + 2*128*200, nullptr, bb & 7, bb >> 3, a.t0, a.TC, a.Tlast, smem);
  } else {
    const int bb = b - 160;
    rec_stage<200, 224, 10, true>(nullptr, a.Wx3, a.Wh3, a.b3, 200,
        a.Hx2, a.Hx3, a.flags + 256, a.flags + 384, nullptr, 10, 0,
        a.cst + 3*128*200, a.hlast, bb & 7, bb >> 3, a.t0, a.TC, a.Tlast, smem);
  }
}

// ---------------------------------------------------------------------------
__global__ __launch_bounds__(256) void head_kernel(
    const float* __restrict__ hlast, const float* __restrict__ Wd,
    const float* __restrict__ bd, float* __restrict__ out)
{
  const int e = blockIdx.x*256 + threadIdx.x;
  if (e >= 128*6) return;
  const int b = e / 6, o = e - 6*b;
  float s = bd[o];
  const float* hp = hlast + (size_t)b*200;
  for (int k = 0; k < 200; ++k) s += hp[k] * Wd[k*6 + o];
  out[e] = s;
}

__global__ void fill_sentinel(float* out, int n){
  const int i = blockIdx.x*blockDim.x + threadIdx.x;
  if (i < n) out[i] = 1.0e30f;
}

// ---------------------------------------------------------------------------
extern "C" void kernel_launch(void* const* d_in, const int* in_sizes, int n_in,
                              void* d_out, int out_size, void* d_ws, size_t ws_size,
                              hipStream_t stream)
{
  (void)in_sizes; (void)n_in;
  const float* xs  = (const float*)d_in[0];
  const float* Wx[4] = {(const float*)d_in[1], (const float*)d_in[4],
                        (const float*)d_in[7], (const float*)d_in[10]};
  const float* Wh[4] = {(const float*)d_in[2], (const float*)d_in[5],
                        (const float*)d_in[8], (const float*)d_in[11]};
  const float* bs[4] = {(const float*)d_in[3], (const float*)d_in[6],
                        (const float*)d_in[9], (const float*)d_in[12]};
  const float* Wd = (const float*)d_in[13];
  const float* bd = (const float*)d_in[14];
  float* out = (float*)d_out;

  // ---- workspace layout ----
  // Hx per layer (u32): H=100 -> 2*8*2*16*64 = 32768 ; H=200 -> 2*8*2*16*112 = 57344
  char* ws = (char*)d_ws;
  const size_t HXU[4] = {32768, 32768, 57344, 57344};
  size_t off = 0;
  const size_t OFF_FLAGS = off; off += (size_t)4*128*4;
  const size_t OFF_HX    = off; off += (HXU[0]+HXU[1]+HXU[2]+HXU[3])*4;
  const size_t OFF_CST   = off; off += (size_t)4*128*200*4;
  const size_t OFF_HLAST = off; off += (size_t)128*200*4;
  off = (off + 255) & ~(size_t)255;
  const size_t FIXED_END = off;

  int CT = 0;
  for (int ct = 1024; ct >= 8; ct >>= 1){
    const size_t need = FIXED_END + (size_t)ct*128*400*4;   // G0 chunk only
    if (ws_size >= need){ CT = ct; break; }
  }
  if (CT == 0){
    fill_sentinel<<<(out_size + 255)/256, 256, 0, stream>>>(out, out_size);
    return;
  }

  unsigned* flags = (unsigned*)(ws + OFF_FLAGS);
  unsigned* Hx0   = (unsigned*)(ws + OFF_HX);
  unsigned* Hx1   = Hx0 + HXU[0];
  unsigned* Hx2   = Hx1 + HXU[1];
  unsigned* Hx3   = Hx2 + HXU[2];
  float* cst      = (float*)(ws + OFF_CST);
  float* hlast    = (float*)(ws + OFF_HLAST);
  float* G0       = (float*)(ws + FIXED_END);

  // L3 stage LDS: 2 planes * 80*(448+8)*2B + zbuf 16*80*4B = 151,040
  const int FUSED_LDS = 151040;
  hipFuncSetAttribute(reinterpret_cast<const void*>(lstm_fused),
                      hipFuncAttributeMaxDynamicSharedMemorySize, FUSED_LDS);

  hipMemsetAsync(flags, 0, 4*128*4, stream);
  hipMemsetAsync(Hx0, 0, (HXU[0]+HXU[1]+HXU[2]+HXU[3])*4, stream);

  FusedArgs fa;
  fa.Wx1 = Wx[1]; fa.Wx2 = Wx[2]; fa.Wx3 = Wx[3];
  fa.Wh0 = Wh[0]; fa.Wh1 = Wh[1]; fa.Wh2 = Wh[2]; fa.Wh3 = Wh[3];
  fa.b1 = bs[1];  fa.b2 = bs[2];  fa.b3 = bs[3];
  fa.Hx0 = Hx0; fa.Hx1 = Hx1; fa.Hx2 = Hx2; fa.Hx3 = Hx3;
  fa.flags = flags; fa.cst = cst; fa.hlast = hlast;
  fa.G0 = G0; fa.Tlast = 1024;

  const int NC  = 1024 / CT;
  const int GMX = CT*128/256;
  for (int c = 0; c < NC; ++c){
    const int t0 = c*CT;
    // layer-0 pregate for this chunk: xs[b][t][d], K=128, N=400
    gemm_pregate<<<dim3(GMX,5), 256, 0, stream>>>(xs + (size_t)t0*128, Wx[0], bs[0], G0,
        128, 4, 400, (size_t)128, (size_t)131072);
    fa.t0 = t0; fa.TC = CT;
    lstm_fused<<<240, 256, FUSED_LDS, stream>>>(fa);
  }

  head_kernel<<<3, 256, 0, stream>>>(hlast, Wd, bd, out);
}

// Round 5
// 7153.810 us; speedup vs baseline: 9.7883x; 1.2136x over previous
//
#include <hip/hip_runtime.h>
#include <cstdint>
#include <cstddef>

// ============================================================================
// 4-layer LSTM (B=128, T=1024, D=128, H={100,100,200,200}) + linear head.
// R5: fused persistent pipeline, per-step critical path minimized.
//  - phase A: wait upstream flag (early in steady state) -> x-part MFMA
//  - phase B: wait own members -> own-h MFMA -> gates -> publish
//  - h window: 8 slots per layer (slot = t mod 8) -> elastic backpressure
//    (down check flg >= t-7, never spins in steady state)
//  - waits run in different waves (concurrent SIMDs, no divergent serialization)
// All matmul math bf16x3 (hi*hi + lo*hi + hi*lo) accumulated fp32.
// ============================================================================

#define AGENT __HIP_MEMORY_SCOPE_AGENT

typedef __attribute__((ext_vector_type(8))) short  short8;
typedef __attribute__((ext_vector_type(4))) float  f32x4;

struct us4 { unsigned short x, y, z, w; };

__device__ __forceinline__ unsigned short f2bf(float x){
  unsigned u = __float_as_uint(x);
  unsigned r = u + 0x7FFFu + ((u >> 16) & 1u);   // RN-even to bf16
  return (unsigned short)(r >> 16);
}
__device__ __forceinline__ float bf2f(unsigned short h){
  return __uint_as_float(((unsigned)h) << 16);
}
__device__ __forceinline__ float sigmoidf_(float x){ return 1.f / (1.f + __expf(-x)); }

__device__ __forceinline__ void spin_ge(const unsigned* p, unsigned v){
  long s = 0;
  while (__hip_atomic_load(p, __ATOMIC_RELAXED, AGENT) < v){
    if (++s > (1L << 24)) break;   // safety valve
  }
}

__device__ __forceinline__ void load_hx(const unsigned* base, int w32, int loOff,
                                        short8& ah, short8& al){
  union U { unsigned long long q[2]; short8 v; } uh, ul;
  const unsigned long long* ph = (const unsigned long long*)(base + w32);
  const unsigned long long* pl = (const unsigned long long*)(base + loOff + w32);
  uh.q[0] = __hip_atomic_load(ph + 0, __ATOMIC_RELAXED, AGENT);
  uh.q[1] = __hip_atomic_load(ph + 1, __ATOMIC_RELAXED, AGENT);
  ul.q[0] = __hip_atomic_load(pl + 0, __ATOMIC_RELAXED, AGENT);
  ul.q[1] = __hip_atomic_load(pl + 1, __ATOMIC_RELAXED, AGENT);
  ah = uh.v; al = ul.v;
}

// ---------------------------------------------------------------------------
// K1: pregate GEMM for layer 0 only.  G[m][n] = xs_row(m) @ Wx0 + b0.
// ---------------------------------------------------------------------------
__global__ __launch_bounds__(256) void gemm_pregate(
    const float* __restrict__ A, const float* __restrict__ W,
    const float* __restrict__ bias, float* __restrict__ G,
    int K, int KT, int N, size_t strideT, size_t strideB)
{
  __shared__ unsigned short Ahi[256*40];
  __shared__ unsigned short Alo[256*40];
  __shared__ unsigned short Bhi[80*40];
  __shared__ unsigned short Blo[80*40];

  const int tid  = threadIdx.x;
  const int mb   = blockIdx.x;
  const int n0   = blockIdx.y * 80;
  const int wave = tid >> 6, lane = tid & 63;
  const int ln15 = lane & 15, quad = lane >> 4;

  f32x4 acc[4][5];
  for (int a = 0; a < 4; ++a)
    for (int b = 0; b < 5; ++b)
      acc[a][b] = (f32x4){0.f, 0.f, 0.f, 0.f};

  for (int kt = 0; kt < KT; ++kt){
    const int k0 = kt * 32;
    const bool full = (k0 + 31) < K;
    for (int i = 0; i < 8; ++i){
      const int e   = tid + 256*i;
      const int row = e >> 3, seg = e & 7;
      const int mm  = mb*256 + row;
      const float* rp = A + (size_t)(mm >> 7)*strideT + (size_t)(mm & 127)*strideB;
      const int k = k0 + seg*4;
      float v0, v1, v2, v3;
      if (full){
        float4 v = *(const float4*)(rp + k);
        v0 = v.x; v1 = v.y; v2 = v.z; v3 = v.w;
      } else {
        v0 = (k+0 < K) ? rp[k+0] : 0.f;
        v1 = (k+1 < K) ? rp[k+1] : 0.f;
        v2 = (k+2 < K) ? rp[k+2] : 0.f;
        v3 = (k+3 < K) ? rp[k+3] : 0.f;
      }
      const unsigned short h0=f2bf(v0), h1=f2bf(v1), h2=f2bf(v2), h3=f2bf(v3);
      us4 hv{h0, h1, h2, h3};
      us4 lv{f2bf(v0-bf2f(h0)), f2bf(v1-bf2f(h1)), f2bf(v2-bf2f(h2)), f2bf(v3-bf2f(h3))};
      *(us4*)&Ahi[row*40 + seg*4] = hv;
      *(us4*)&Alo[row*40 + seg*4] = lv;
    }
    for (int i = 0; i < 10; ++i){
      const int e  = tid + 256*i;
      const int kk = e / 80, nn = e - kk*80;
      const int k  = k0 + kk;
      const float v = (k < K) ? W[(size_t)k*N + n0 + nn] : 0.f;
      const unsigned short hb = f2bf(v);
      Bhi[nn*40 + kk] = hb;
      Blo[nn*40 + kk] = f2bf(v - bf2f(hb));
    }
    __syncthreads();
    short8 a_h[4], a_l[4];
    for (int mt = 0; mt < 4; ++mt){
      const int aoff = (wave*64 + mt*16 + ln15)*40 + quad*8;
      a_h[mt] = *(const short8*)&Ahi[aoff];
      a_l[mt] = *(const short8*)&Alo[aoff];
    }
    for (int nt = 0; nt < 5; ++nt){
      const int boff = (nt*16 + ln15)*40 + quad*8;
      const short8 b_h = *(const short8*)&Bhi[boff];
      const short8 b_l = *(const short8*)&Blo[boff];
      for (int mt = 0; mt < 4; ++mt){
        acc[mt][nt] = __builtin_amdgcn_mfma_f32_16x16x32_bf16(a_h[mt], b_h, acc[mt][nt], 0,0,0);
        acc[mt][nt] = __builtin_amdgcn_mfma_f32_16x16x32_bf16(a_l[mt], b_h, acc[mt][nt], 0,0,0);
        acc[mt][nt] = __builtin_amdgcn_mfma_f32_16x16x32_bf16(a_h[mt], b_l, acc[mt][nt], 0,0,0);
      }
    }
    __syncthreads();
  }
  for (int nt = 0; nt < 5; ++nt){
    const float bv = bias[n0 + nt*16 + ln15];
    for (int mt = 0; mt < 4; ++mt){
      const int mbase = mb*256 + wave*64 + mt*16 + quad*4;
      #pragma unroll
      for (int r = 0; r < 4; ++r)
        G[(size_t)(mbase + r)*N + n0 + nt*16 + ln15] = acc[mt][nt][r] + bv;
    }
  }
}

// ---------------------------------------------------------------------------
// Fused pipeline stage (window-8 h slots, two-phase waits).
// Hx layout per layer: [slot(8)][group(8)][plane hi/lo][16 rows][RS u32].
// Slot s holds h_t for t ≡ s (mod 8). h_{-1} = zeros (slot 7 at t=0, memset).
// ---------------------------------------------------------------------------
template<int H, int HP, int P, bool HAS_X>
__device__ __forceinline__ void rec_stage(
    const float* __restrict__ G0, const float* __restrict__ Wx,
    const float* __restrict__ Wh, const float* __restrict__ bias,
    int HprevReal,
    const unsigned* __restrict__ HxUp, unsigned* __restrict__ HxOwn,
    const unsigned* __restrict__ flgUp, unsigned* __restrict__ flgOwn,
    unsigned* __restrict__ flgDn, int PUp, int PDn,
    float* __restrict__ cstate, float* __restrict__ hlast,
    int g, int m, int t0, int TC, int Tlast, char* smem)
{
  constexpr int HHM  = H / P;                 // 20
  constexpr int COLS = 4 * HHM;               // 80
  constexpr int CP   = COLS;
  constexpr int ZSTR = CP + 1;                // zbuf row stride (pad)
  constexpr int KPo  = ((H + 31)/32)*32;      // own-h padded K
  constexpr int RSo  = KPo / 2;               // own Hx row stride (u32)
  constexpr int RSp  = HP / 2;                // upstream Hx row stride
  constexpr int KX   = HAS_X ? HP : 0;
  constexpr int KALL = KX + KPo;
  constexpr int KTX  = KX / 32;
  constexpr int KTH  = KPo / 32;
  constexpr int KSTR = KALL + 8;
  constexpr int NT   = CP / 16;               // 5
  constexpr int NE   = 16 * HHM / 2;          // 160
  constexpr int PR   = HHM / 2;               // 10
  constexpr int N4H  = 4 * H;
  constexpr int SLOTo = 2*16*RSo;             // u32 per (slot,group), own
  constexpr int SLOTp = 2*16*RSp;             // u32 per (slot,group), upstream

  unsigned short* whT_hi = (unsigned short*)smem;
  unsigned short* whT_lo = whT_hi + CP*KSTR;
  float* zbuf = (float*)(whT_lo + CP*KSTR);   // [16][ZSTR]

  const int tid  = threadIdx.x;
  const int row0 = g * 16;
  const int lane = tid & 63, wave = tid >> 6;
  const int ln15 = lane & 15, quad = lane >> 4;

  // stage concatenated weight strip [col][k], hi/lo bf16 (zeros in pad rows)
  for (int e = tid; e < COLS*KALL; e += 256){
    const int k = e / COLS, c = e - k*COLS;
    const int gate = c / HHM, hh = c - gate*HHM;
    const int col = gate*H + m*HHM + hh;
    float w = 0.f;
    if (HAS_X){
      if (k < KX){ if (k < HprevReal) w = Wx[(size_t)k*N4H + col]; }
      else { const int k2 = k - KX; if (k2 < H) w = Wh[(size_t)k2*N4H + col]; }
    } else {
      if (k < H) w = Wh[(size_t)k*N4H + col];
    }
    const unsigned short hi = f2bf(w);
    whT_hi[c*KSTR + k] = hi;
    whT_lo[c*KSTR + k] = f2bf(w - bf2f(hi));
  }

  const int r_g  = tid / PR;
  const int hh0  = 2*(tid - r_g*PR);
  const int kidx = m*HHM + hh0;
  float c0 = 0.f, c1 = 0.f;
  if (tid < NE && t0 > 0){
    const float2 cv = *(const float2*)&cstate[(size_t)(row0 + r_g)*H + kidx];
    c0 = cv.x; c1 = cv.y;
  }
  float2 bv[4] = {};
  if (HAS_X){
    if (tid < NE){
      #pragma unroll
      for (int gate = 0; gate < 4; ++gate)
        bv[gate] = *(const float2*)&bias[gate*H + kidx];
    }
  }
  __syncthreads();

  const int g16 = g*16;

  for (int tl = 0; tl < TC; ++tl){
    const int t = t0 + tl;

    // layer-0 pregate values (independent of h; overlaps the waits)
    float2 gv[4] = {};
    if constexpr (!HAS_X){
      if (tid < NE){
        const float* Gt = G0 + ((size_t)tl*128 + row0 + r_g)*(size_t)N4H + kidx;
        #pragma unroll
        for (int gate = 0; gate < 4; ++gate)
          gv[gate] = *(const float2*)(Gt + gate*H);
      }
    }

    // ---- phase A: upstream + backpressure waits (separate waves) ----
    if (HAS_X && wave == 0 && lane < PUp)
      spin_ge(&flgUp[g16 + lane], (unsigned)(t+1));       // x_t = h^up_t ready
    if (PDn > 0 && t >= 8 && wave == 1 && lane < PDn)
      spin_ge(&flgDn[g16 + lane], (unsigned)(t-7));       // slot t&7 free
    __syncthreads();

    f32x4 acc[2];
    acc[0] = (f32x4){0.f,0.f,0.f,0.f};
    acc[1] = (f32x4){0.f,0.f,0.f,0.f};
    auto do_tile = [&](const short8& a_h, const short8& a_l, int koW){
      #pragma unroll
      for (int s = 0; s < 2; ++s){
        const int nt = wave + 4*s;
        if (nt < NT){
          const int boff = (nt*16 + ln15)*KSTR + quad*8 + koW;
          const short8 b_h = *(const short8*)&whT_hi[boff];
          const short8 b_l = *(const short8*)&whT_lo[boff];
          acc[s] = __builtin_amdgcn_mfma_f32_16x16x32_bf16(a_h, b_h, acc[s], 0,0,0);
          acc[s] = __builtin_amdgcn_mfma_f32_16x16x32_bf16(a_l, b_h, acc[s], 0,0,0);
          acc[s] = __builtin_amdgcn_mfma_f32_16x16x32_bf16(a_h, b_l, acc[s], 0,0,0);
        }
      }
    };

    // x-part MFMA: overlaps own members finishing h_t publication
    if constexpr (HAS_X){
      const unsigned* up = HxUp + ((size_t)(t & 7)*8 + g) * SLOTp;
      #pragma unroll
      for (int kt = 0; kt < KTX; ++kt){
        short8 a_h, a_l;
        load_hx(up, ln15*RSp + kt*16 + quad*4, 16*RSp, a_h, a_l);
        do_tile(a_h, a_l, kt*32);
      }
    }

    // ---- phase B: own-member wait, then own-h part ----
    if (wave == 0 && lane < P)
      spin_ge(&flgOwn[g16 + lane], (unsigned)t);          // h_{t-1} ready
    __syncthreads();

    {
      const unsigned* own = HxOwn + ((size_t)((t-1) & 7)*8 + g) * SLOTo;
      #pragma unroll
      for (int kt = 0; kt < KTH; ++kt){
        short8 a_h, a_l;
        load_hx(own, ln15*RSo + kt*16 + quad*4, 16*RSo, a_h, a_l);
        do_tile(a_h, a_l, KX + kt*32);
      }
    }
    {
      #pragma unroll
      for (int s = 0; s < 2; ++s){
        const int nt = wave + 4*s;
        if (nt < NT)
          #pragma unroll
          for (int r = 0; r < 4; ++r)
            zbuf[(quad*4 + r)*ZSTR + nt*16 + ln15] = acc[s][r];
      }
    }
    __syncthreads();

    // gates + state update + publish h_t -> own slot t&7
    if (tid < NE){
      const float* zr = zbuf + r_g*ZSTR;
      const float2 b0 = HAS_X ? bv[0] : gv[0];
      const float2 b1 = HAS_X ? bv[1] : gv[1];
      const float2 b2 = HAS_X ? bv[2] : gv[2];
      const float2 b3 = HAS_X ? bv[3] : gv[3];
      const float zi0 = zr[0*HHM + hh0]   + b0.x, zi1 = zr[0*HHM + hh0+1] + b0.y;
      const float zf0 = zr[1*HHM + hh0]   + b1.x, zf1 = zr[1*HHM + hh0+1] + b1.y;
      const float zg0 = zr[2*HHM + hh0]   + b2.x, zg1 = zr[2*HHM + hh0+1] + b2.y;
      const float zo0 = zr[3*HHM + hh0]   + b3.x, zo1 = zr[3*HHM + hh0+1] + b3.y;
      c0 = sigmoidf_(zf0)*c0 + sigmoidf_(zi0)*tanhf(zg0);
      c1 = sigmoidf_(zf1)*c1 + sigmoidf_(zi1)*tanhf(zg1);
      const float h0 = sigmoidf_(zo0)*tanhf(c0);
      const float h1 = sigmoidf_(zo1)*tanhf(c1);
      const unsigned short h0h = f2bf(h0), h1h = f2bf(h1);
      const unsigned short h0l = f2bf(h0 - bf2f(h0h)), h1l = f2bf(h1 - bf2f(h1h));
      const unsigned whi = ((unsigned)h1h << 16) | (unsigned)h0h;
      const unsigned wlo = ((unsigned)h1l << 16) | (unsigned)h0l;
      unsigned* dst = HxOwn + ((size_t)(t & 7)*8 + g) * SLOTo;
      const int w32 = r_g*RSo + (kidx >> 1);
      __hip_atomic_store(&dst[w32],          whi, __ATOMIC_RELAXED, AGENT);
      __hip_atomic_store(&dst[16*RSo + w32], wlo, __ATOMIC_RELAXED, AGENT);
      if (hlast && t == Tlast-1){
        float2 hv{h0, h1};
        *(float2*)&hlast[(size_t)(row0 + r_g)*H + kidx] = hv;
      }
    }
    __syncthreads();   // vmcnt(0)-drain per wave => h stores LLC-visible
    if (tid == 0)
      __hip_atomic_store(&flgOwn[g16 + m], (unsigned)(t+1), __ATOMIC_RELAXED, AGENT);
  }

  // persist c-state for the next chunk
  if (tid < NE){
    float2 cv{c0, c1};
    *(float2*)&cstate[(size_t)(row0 + r_g)*H + kidx] = cv;
  }
}

struct FusedArgs {
  const float *G0;
  const float *Wx1, *Wx2, *Wx3;
  const float *Wh0, *Wh1, *Wh2, *Wh3;
  const float *b1, *b2, *b3;
  unsigned *Hx0, *Hx1, *Hx2, *Hx3;
  unsigned *flags;                 // 4 layers x 128 u32
  float *cst;                      // 4 x 128 x 200
  float *hlast;
  int t0, TC, Tlast;
};

// Blocks: [0,40)=L0, [40,80)=L1, [80,160)=L2, [160,240)=L3.
__global__ __launch_bounds__(256) void lstm_fused(FusedArgs a){
  extern __shared__ char smem[];
  const int b = blockIdx.x;
  if (b < 40){
    rec_stage<100, 0, 5, false>(a.G0, nullptr, a.Wh0, nullptr, 0,
        nullptr, a.Hx0, nullptr, a.flags + 0, a.flags + 128, 0, 5,
        a.cst + 0*128*200, nullptr, b & 7, b >> 3, a.t0, a.TC, a.Tlast, smem);
  } else if (b < 80){
    const int bb = b - 40;
    rec_stage<100, 128, 5, true>(nullptr, a.Wx1, a.Wh1, a.b1, 100,
        a.Hx0, a.Hx1, a.flags + 0, a.flags + 128, a.flags + 256, 5, 10,
        a.cst + 1*128*200, nullptr, bb & 7, bb >> 3, a.t0, a.TC, a.Tlast, smem);
  } else if (b < 160){
    const int bb = b - 80;
    rec_stage<200, 128, 10, true>(nullptr, a.Wx2, a.Wh2, a.b2, 100,
        a.Hx1, a.Hx2, a.flags + 128, a.flags + 256, a.flags + 384, 5, 10,
        a.cst + 2*128*200, nullptr, bb & 7, bb >> 3, a.t0, a.TC, a.Tlast, smem);
  } else {
    const int bb = b - 160;
    rec_stage<200, 224, 10, true>(nullptr, a.Wx3, a.Wh3, a.b3, 200,
        a.Hx2, a.Hx3, a.flags + 256, a.flags + 384, nullptr, 10, 0,
        a.cst + 3*128*200, a.hlast, bb & 7, bb >> 3, a.t0, a.TC, a.Tlast, smem);
  }
}

// ---------------------------------------------------------------------------
__global__ __launch_bounds__(256) void head_kernel(
    const float* __restrict__ hlast, const float* __restrict__ Wd,
    const float* __restrict__ bd, float* __restrict__ out)
{
  const int e = blockIdx.x*256 + threadIdx.x;
  if (e >= 128*6) return;
  const int b = e / 6, o = e - 6*b;
  float s = bd[o];
  const float* hp = hlast + (size_t)b*200;
  for (int k = 0; k < 200; ++k) s += hp[k] * Wd[k*6 + o];
  out[e] = s;
}

__global__ void fill_sentinel(float* out, int n){
  const int i = blockIdx.x*blockDim.x + threadIdx.x;
  if (i < n) out[i] = 1.0e30f;
}

// ---------------------------------------------------------------------------
extern "C" void kernel_launch(void* const* d_in, const int* in_sizes, int n_in,
                              void* d_out, int out_size, void* d_ws, size_t ws_size,
                              hipStream_t stream)
{
  (void)in_sizes; (void)n_in;
  const float* xs  = (const float*)d_in[0];
  const float* Wx[4] = {(const float*)d_in[1], (const float*)d_in[4],
                        (const float*)d_in[7], (const float*)d_in[10]};
  const float* Wh[4] = {(const float*)d_in[2], (const float*)d_in[5],
                        (const float*)d_in[8], (const float*)d_in[11]};
  const float* bs[4] = {(const float*)d_in[3], (const float*)d_in[6],
                        (const float*)d_in[9], (const float*)d_in[12]};
  const float* Wd = (const float*)d_in[13];
  const float* bd = (const float*)d_in[14];
  float* out = (float*)d_out;

  // ---- workspace layout ----
  // Hx per layer (u32), 8 slots x 8 groups x 2 planes x 16 rows x RS:
  //   H=100 (RS=64):  8*8*2048  = 131072 u32
  //   H=200 (RS=112): 8*8*3584  = 229376 u32
  char* ws = (char*)d_ws;
  const size_t HXU[4] = {131072, 131072, 229376, 229376};
  const size_t HX_TOT = HXU[0]+HXU[1]+HXU[2]+HXU[3];     // 720896 u32
  size_t off = 0;
  const size_t OFF_FLAGS = off; off += (size_t)4*128*4;
  const size_t OFF_HX    = off; off += HX_TOT*4;
  const size_t OFF_CST   = off; off += (size_t)4*128*200*4;
  const size_t OFF_HLAST = off; off += (size_t)128*200*4;
  off = (off + 255) & ~(size_t)255;
  const size_t FIXED_END = off;

  int CT = 0;
  for (int ct = 1024; ct >= 8; ct >>= 1){
    const size_t need = FIXED_END + (size_t)ct*128*400*4;   // G0 chunk only
    if (ws_size >= need){ CT = ct; break; }
  }
  if (CT == 0){
    fill_sentinel<<<(out_size + 255)/256, 256, 0, stream>>>(out, out_size);
    return;
  }

  unsigned* flags = (unsigned*)(ws + OFF_FLAGS);
  unsigned* Hx0   = (unsigned*)(ws + OFF_HX);
  unsigned* Hx1   = Hx0 + HXU[0];
  unsigned* Hx2   = Hx1 + HXU[1];
  unsigned* Hx3   = Hx2 + HXU[2];
  float* cst      = (float*)(ws + OFF_CST);
  float* hlast    = (float*)(ws + OFF_HLAST);
  float* G0       = (float*)(ws + FIXED_END);

  // L3 stage LDS: 2 planes * 80*456 shorts = 145920 B + zbuf 16*81*4 = 5184
  const int FUSED_LDS = 151104;
  hipFuncSetAttribute(reinterpret_cast<const void*>(lstm_fused),
                      hipFuncAttributeMaxDynamicSharedMemorySize, FUSED_LDS);

  hipMemsetAsync(flags, 0, 4*128*4, stream);
  hipMemsetAsync(Hx0, 0, HX_TOT*4, stream);

  FusedArgs fa;
  fa.Wx1 = Wx[1]; fa.Wx2 = Wx[2]; fa.Wx3 = Wx[3];
  fa.Wh0 = Wh[0]; fa.Wh1 = Wh[1]; fa.Wh2 = Wh[2]; fa.Wh3 = Wh[3];
  fa.b1 = bs[1];  fa.b2 = bs[2];  fa.b3 = bs[3];
  fa.Hx0 = Hx0; fa.Hx1 = Hx1; fa.Hx2 = Hx2; fa.Hx3 = Hx3;
  fa.flags = flags; fa.cst = cst; fa.hlast = hlast;
  fa.G0 = G0; fa.Tlast = 1024;

  const int NC  = 1024 / CT;
  const int GMX = CT*128/256;
  for (int c = 0; c < NC; ++c){
    const int t0 = c*CT;
    // layer-0 pregate for this chunk: xs[b][t][d], K=128, N=400
    gemm_pregate<<<dim3(GMX,5), 256, 0, stream>>>(xs + (size_t)t0*128, Wx[0], bs[0], G0,
        128, 4, 400, (size_t)128, (size_t)131072);
    fa.t0 = t0; fa.TC = CT;
    lstm_fused<<<240, 256, FUSED_LDS, stream>>>(fa);
  }

  head_kernel<<<3, 256, 0, stream>>>(hlast, Wd, bd, out);
}

// Round 7
// 6549.257 us; speedup vs baseline: 10.6919x; 1.0923x over previous
//
#include <hip/hip_runtime.h>
#include <cstdint>
#include <cstddef>

// ============================================================================
// 4-layer LSTM (B=128, T=1024, D=128, H={100,100,200,200}) + linear head.
// R7 = R5 (known-good fused pipeline) + two contention fixes:
//  - each sync flag padded to its own 256B sector (64-u32 stride) to spread
//    LLC lines/banks,
//  - sleep-backoff polling (32 fast probes then s_sleep(8) loop) to cut
//    poll traffic ~10x.
// Protocol identical to R5: window-8 h slots, relaxed agent atomics, phase A
// (up/down wait -> x-part MFMA) / phase B (own wait -> own-h MFMA), bf16x3.
// ============================================================================

#define AGENT __HIP_MEMORY_SCOPE_AGENT
#define FSTR 64   // u32 stride between flags (256B sector per flag)

typedef __attribute__((ext_vector_type(8))) short  short8;
typedef __attribute__((ext_vector_type(4))) float  f32x4;

struct us4 { unsigned short x, y, z, w; };

__device__ __forceinline__ unsigned short f2bf(float x){
  unsigned u = __float_as_uint(x);
  unsigned r = u + 0x7FFFu + ((u >> 16) & 1u);   // RN-even to bf16
  return (unsigned short)(r >> 16);
}
__device__ __forceinline__ float bf2f(unsigned short h){
  return __uint_as_float(((unsigned)h) << 16);
}
__device__ __forceinline__ float sigmoidf_(float x){ return 1.f / (1.f + __expf(-x)); }

__device__ __forceinline__ void spin_ge(const unsigned* p, unsigned v){
  #pragma unroll 1
  for (int i = 0; i < 32; ++i){
    if (__hip_atomic_load(p, __ATOMIC_RELAXED, AGENT) >= v) return;
  }
  long s = 0;
  #pragma unroll 1
  while (__hip_atomic_load(p, __ATOMIC_RELAXED, AGENT) < v){
    __builtin_amdgcn_s_sleep(8);               // ~0.2us backoff
    if (++s > (1L << 17)) break;               // fail fast on true deadlock
  }
}

__device__ __forceinline__ void load_hx(const unsigned* base, int w32, int loOff,
                                        short8& ah, short8& al){
  union U { unsigned long long q[2]; short8 v; } uh, ul;
  const unsigned long long* ph = (const unsigned long long*)(base + w32);
  const unsigned long long* pl = (const unsigned long long*)(base + loOff + w32);
  uh.q[0] = __hip_atomic_load(ph + 0, __ATOMIC_RELAXED, AGENT);
  uh.q[1] = __hip_atomic_load(ph + 1, __ATOMIC_RELAXED, AGENT);
  ul.q[0] = __hip_atomic_load(pl + 0, __ATOMIC_RELAXED, AGENT);
  ul.q[1] = __hip_atomic_load(pl + 1, __ATOMIC_RELAXED, AGENT);
  ah = uh.v; al = ul.v;
}

// ---------------------------------------------------------------------------
// K1: pregate GEMM for layer 0 only.  G[m][n] = xs_row(m) @ Wx0 + b0.
// ---------------------------------------------------------------------------
__global__ __launch_bounds__(256) void gemm_pregate(
    const float* __restrict__ A, const float* __restrict__ W,
    const float* __restrict__ bias, float* __restrict__ G,
    int K, int KT, int N, size_t strideT, size_t strideB)
{
  __shared__ unsigned short Ahi[256*40];
  __shared__ unsigned short Alo[256*40];
  __shared__ unsigned short Bhi[80*40];
  __shared__ unsigned short Blo[80*40];

  const int tid  = threadIdx.x;
  const int mb   = blockIdx.x;
  const int n0   = blockIdx.y * 80;
  const int wave = tid >> 6, lane = tid & 63;
  const int ln15 = lane & 15, quad = lane >> 4;

  f32x4 acc[4][5];
  for (int a = 0; a < 4; ++a)
    for (int b = 0; b < 5; ++b)
      acc[a][b] = (f32x4){0.f, 0.f, 0.f, 0.f};

  for (int kt = 0; kt < KT; ++kt){
    const int k0 = kt * 32;
    const bool full = (k0 + 31) < K;
    for (int i = 0; i < 8; ++i){
      const int e   = tid + 256*i;
      const int row = e >> 3, seg = e & 7;
      const int mm  = mb*256 + row;
      const float* rp = A + (size_t)(mm >> 7)*strideT + (size_t)(mm & 127)*strideB;
      const int k = k0 + seg*4;
      float v0, v1, v2, v3;
      if (full){
        float4 v = *(const float4*)(rp + k);
        v0 = v.x; v1 = v.y; v2 = v.z; v3 = v.w;
      } else {
        v0 = (k+0 < K) ? rp[k+0] : 0.f;
        v1 = (k+1 < K) ? rp[k+1] : 0.f;
        v2 = (k+2 < K) ? rp[k+2] : 0.f;
        v3 = (k+3 < K) ? rp[k+3] : 0.f;
      }
      const unsigned short h0=f2bf(v0), h1=f2bf(v1), h2=f2bf(v2), h3=f2bf(v3);
      us4 hv{h0, h1, h2, h3};
      us4 lv{f2bf(v0-bf2f(h0)), f2bf(v1-bf2f(h1)), f2bf(v2-bf2f(h2)), f2bf(v3-bf2f(h3))};
      *(us4*)&Ahi[row*40 + seg*4] = hv;
      *(us4*)&Alo[row*40 + seg*4] = lv;
    }
    for (int i = 0; i < 10; ++i){
      const int e  = tid + 256*i;
      const int kk = e / 80, nn = e - kk*80;
      const int k  = k0 + kk;
      const float v = (k < K) ? W[(size_t)k*N + n0 + nn] : 0.f;
      const unsigned short hb = f2bf(v);
      Bhi[nn*40 + kk] = hb;
      Blo[nn*40 + kk] = f2bf(v - bf2f(hb));
    }
    __syncthreads();
    short8 a_h[4], a_l[4];
    for (int mt = 0; mt < 4; ++mt){
      const int aoff = (wave*64 + mt*16 + ln15)*40 + quad*8;
      a_h[mt] = *(const short8*)&Ahi[aoff];
      a_l[mt] = *(const short8*)&Alo[aoff];
    }
    for (int nt = 0; nt < 5; ++nt){
      const int boff = (nt*16 + ln15)*40 + quad*8;
      const short8 b_h = *(const short8*)&Bhi[boff];
      const short8 b_l = *(const short8*)&Blo[boff];
      for (int mt = 0; mt < 4; ++mt){
        acc[mt][nt] = __builtin_amdgcn_mfma_f32_16x16x32_bf16(a_h[mt], b_h, acc[mt][nt], 0,0,0);
        acc[mt][nt] = __builtin_amdgcn_mfma_f32_16x16x32_bf16(a_l[mt], b_h, acc[mt][nt], 0,0,0);
        acc[mt][nt] = __builtin_amdgcn_mfma_f32_16x16x32_bf16(a_h[mt], b_l, acc[mt][nt], 0,0,0);
      }
    }
    __syncthreads();
  }
  for (int nt = 0; nt < 5; ++nt){
    const float bv = bias[n0 + nt*16 + ln15];
    for (int mt = 0; mt < 4; ++mt){
      const int mbase = mb*256 + wave*64 + mt*16 + quad*4;
      #pragma unroll
      for (int r = 0; r < 4; ++r)
        G[(size_t)(mbase + r)*N + n0 + nt*16 + ln15] = acc[mt][nt][r] + bv;
    }
  }
}

// ---------------------------------------------------------------------------
// Fused pipeline stage (window-8 h slots, two-phase waits, padded flags).
// Hx layout per layer: [slot(8)][group(8)][plane hi/lo][16 rows][RS u32].
// Flags: index (g*16 + member) * FSTR.
// ---------------------------------------------------------------------------
template<int H, int HP, int P, bool HAS_X>
__device__ __forceinline__ void rec_stage(
    const float* __restrict__ G0, const float* __restrict__ Wx,
    const float* __restrict__ Wh, const float* __restrict__ bias,
    int HprevReal,
    const unsigned* __restrict__ HxUp, unsigned* __restrict__ HxOwn,
    const unsigned* __restrict__ flgUp, unsigned* __restrict__ flgOwn,
    unsigned* __restrict__ flgDn, int PUp, int PDn,
    float* __restrict__ cstate, float* __restrict__ hlast,
    int g, int m, int t0, int TC, int Tlast, char* smem)
{
  constexpr int HHM  = H / P;                 // 20
  constexpr int COLS = 4 * HHM;               // 80
  constexpr int CP   = COLS;
  constexpr int ZSTR = CP + 1;                // zbuf row stride (pad)
  constexpr int KPo  = ((H + 31)/32)*32;      // own-h padded K
  constexpr int RSo  = KPo / 2;               // own Hx row stride (u32)
  constexpr int RSp  = HP / 2;                // upstream Hx row stride
  constexpr int KX   = HAS_X ? HP : 0;
  constexpr int KALL = KX + KPo;
  constexpr int KTX  = KX / 32;
  constexpr int KTH  = KPo / 32;
  constexpr int KSTR = KALL + 8;
  constexpr int NT   = CP / 16;               // 5
  constexpr int NE   = 16 * HHM / 2;          // 160
  constexpr int PR   = HHM / 2;               // 10
  constexpr int N4H  = 4 * H;
  constexpr int SLOTo = 2*16*RSo;             // u32 per (slot,group), own
  constexpr int SLOTp = 2*16*RSp;             // u32 per (slot,group), upstream

  unsigned short* whT_hi = (unsigned short*)smem;
  unsigned short* whT_lo = whT_hi + CP*KSTR;
  float* zbuf = (float*)(whT_lo + CP*KSTR);   // [16][ZSTR]

  const int tid  = threadIdx.x;
  const int row0 = g * 16;
  const int lane = tid & 63, wave = tid >> 6;
  const int ln15 = lane & 15, quad = lane >> 4;

  // stage concatenated weight strip [col][k], hi/lo bf16 (zeros in pad rows)
  for (int e = tid; e < COLS*KALL; e += 256){
    const int k = e / COLS, c = e - k*COLS;
    const int gate = c / HHM, hh = c - gate*HHM;
    const int col = gate*H + m*HHM + hh;
    float w = 0.f;
    if (HAS_X){
      if (k < KX){ if (k < HprevReal) w = Wx[(size_t)k*N4H + col]; }
      else { const int k2 = k - KX; if (k2 < H) w = Wh[(size_t)k2*N4H + col]; }
    } else {
      if (k < H) w = Wh[(size_t)k*N4H + col];
    }
    const unsigned short hi = f2bf(w);
    whT_hi[c*KSTR + k] = hi;
    whT_lo[c*KSTR + k] = f2bf(w - bf2f(hi));
  }

  const int r_g  = tid / PR;
  const int hh0  = 2*(tid - r_g*PR);
  const int kidx = m*HHM + hh0;
  float c0 = 0.f, c1 = 0.f;
  if (tid < NE && t0 > 0){
    const float2 cv = *(const float2*)&cstate[(size_t)(row0 + r_g)*H + kidx];
    c0 = cv.x; c1 = cv.y;
  }
  float2 bv[4] = {};
  if (HAS_X){
    if (tid < NE){
      #pragma unroll
      for (int gate = 0; gate < 4; ++gate)
        bv[gate] = *(const float2*)&bias[gate*H + kidx];
    }
  }
  __syncthreads();

  const int g16 = g*16;

  for (int tl = 0; tl < TC; ++tl){
    const int t = t0 + tl;

    // layer-0 pregate values (independent of h; overlaps the waits)
    float2 gv[4] = {};
    if constexpr (!HAS_X){
      if (tid < NE){
        const float* Gt = G0 + ((size_t)tl*128 + row0 + r_g)*(size_t)N4H + kidx;
        #pragma unroll
        for (int gate = 0; gate < 4; ++gate)
          gv[gate] = *(const float2*)(Gt + gate*H);
      }
    }

    // ---- phase A: upstream + backpressure waits (separate waves) ----
    if (HAS_X && wave == 0 && lane < PUp)
      spin_ge(&flgUp[(size_t)(g16 + lane)*FSTR], (unsigned)(t+1));  // h^up_t
    if (PDn > 0 && t >= 8 && wave == 1 && lane < PDn)
      spin_ge(&flgDn[(size_t)(g16 + lane)*FSTR], (unsigned)(t-7));  // slot free
    __syncthreads();

    f32x4 acc[2];
    acc[0] = (f32x4){0.f,0.f,0.f,0.f};
    acc[1] = (f32x4){0.f,0.f,0.f,0.f};
    auto do_tile = [&](const short8& a_h, const short8& a_l, int koW){
      #pragma unroll
      for (int s = 0; s < 2; ++s){
        const int nt = wave + 4*s;
        if (nt < NT){
          const int boff = (nt*16 + ln15)*KSTR + quad*8 + koW;
          const short8 b_h = *(const short8*)&whT_hi[boff];
          const short8 b_l = *(const short8*)&whT_lo[boff];
          acc[s] = __builtin_amdgcn_mfma_f32_16x16x32_bf16(a_h, b_h, acc[s], 0,0,0);
          acc[s] = __builtin_amdgcn_mfma_f32_16x16x32_bf16(a_l, b_h, acc[s], 0,0,0);
          acc[s] = __builtin_amdgcn_mfma_f32_16x16x32_bf16(a_h, b_l, acc[s], 0,0,0);
        }
      }
    };

    // x-part MFMA: overlaps own members finishing h_t publication
    if constexpr (HAS_X){
      const unsigned* up = HxUp + ((size_t)(t & 7)*8 + g) * SLOTp;
      #pragma unroll
      for (int kt = 0; kt < KTX; ++kt){
        short8 a_h, a_l;
        load_hx(up, ln15*RSp + kt*16 + quad*4, 16*RSp, a_h, a_l);
        do_tile(a_h, a_l, kt*32);
      }
    }

    // ---- phase B: own-member wait, then own-h part ----
    if (wave == 0 && lane < P)
      spin_ge(&flgOwn[(size_t)(g16 + lane)*FSTR], (unsigned)t);     // h_{t-1}
    __syncthreads();

    {
      const unsigned* own = HxOwn + ((size_t)((t-1) & 7)*8 + g) * SLOTo;
      #pragma unroll
      for (int kt = 0; kt < KTH; ++kt){
        short8 a_h, a_l;
        load_hx(own, ln15*RSo + kt*16 + quad*4, 16*RSo, a_h, a_l);
        do_tile(a_h, a_l, KX + kt*32);
      }
    }
    {
      #pragma unroll
      for (int s = 0; s < 2; ++s){
        const int nt = wave + 4*s;
        if (nt < NT)
          #pragma unroll
          for (int r = 0; r < 4; ++r)
            zbuf[(quad*4 + r)*ZSTR + nt*16 + ln15] = acc[s][r];
      }
    }
    __syncthreads();

    // gates + state update + publish h_t -> own slot t&7
    if (tid < NE){
      const float* zr = zbuf + r_g*ZSTR;
      const float2 b0 = HAS_X ? bv[0] : gv[0];
      const float2 b1 = HAS_X ? bv[1] : gv[1];
      const float2 b2 = HAS_X ? bv[2] : gv[2];
      const float2 b3 = HAS_X ? bv[3] : gv[3];
      const float zi0 = zr[0*HHM + hh0]   + b0.x, zi1 = zr[0*HHM + hh0+1] + b0.y;
      const float zf0 = zr[1*HHM + hh0]   + b1.x, zf1 = zr[1*HHM + hh0+1] + b1.y;
      const float zg0 = zr[2*HHM + hh0]   + b2.x, zg1 = zr[2*HHM + hh0+1] + b2.y;
      const float zo0 = zr[3*HHM + hh0]   + b3.x, zo1 = zr[3*HHM + hh0+1] + b3.y;
      c0 = sigmoidf_(zf0)*c0 + sigmoidf_(zi0)*tanhf(zg0);
      c1 = sigmoidf_(zf1)*c1 + sigmoidf_(zi1)*tanhf(zg1);
      const float h0 = sigmoidf_(zo0)*tanhf(c0);
      const float h1 = sigmoidf_(zo1)*tanhf(c1);
      const unsigned short h0h = f2bf(h0), h1h = f2bf(h1);
      const unsigned short h0l = f2bf(h0 - bf2f(h0h)), h1l = f2bf(h1 - bf2f(h1h));
      const unsigned whi = ((unsigned)h1h << 16) | (unsigned)h0h;
      const unsigned wlo = ((unsigned)h1l << 16) | (unsigned)h0l;
      unsigned* dst = HxOwn + ((size_t)(t & 7)*8 + g) * SLOTo;
      const int w32 = r_g*RSo + (kidx >> 1);
      __hip_atomic_store(&dst[w32],          whi, __ATOMIC_RELAXED, AGENT);
      __hip_atomic_store(&dst[16*RSo + w32], wlo, __ATOMIC_RELAXED, AGENT);
      if (hlast && t == Tlast-1){
        float2 hv{h0, h1};
        *(float2*)&hlast[(size_t)(row0 + r_g)*H + kidx] = hv;
      }
    }
    __syncthreads();   // vmcnt(0)-drain per wave => h stores LLC-visible
    if (tid == 0)
      __hip_atomic_store(&flgOwn[(size_t)(g16 + m)*FSTR], (unsigned)(t+1),
                         __ATOMIC_RELAXED, AGENT);
  }

  // persist c-state for the next chunk
  if (tid < NE){
    float2 cv{c0, c1};
    *(float2*)&cstate[(size_t)(row0 + r_g)*H + kidx] = cv;
  }
}

struct FusedArgs {
  const float *G0;
  const float *Wx1, *Wx2, *Wx3;
  const float *Wh0, *Wh1, *Wh2, *Wh3;
  const float *b1, *b2, *b3;
  unsigned *Hx0, *Hx1, *Hx2, *Hx3;
  unsigned *flags;                 // 4 layers x 128 flags x FSTR u32
  float *cst;                      // 4 x 128 x 200
  float *hlast;
  int t0, TC, Tlast;
};

// Blocks: [0,40)=L0, [40,80)=L1, [80,160)=L2, [160,240)=L3.
__global__ __launch_bounds__(256) void lstm_fused(FusedArgs a){
  extern __shared__ char smem[];
  const int b = blockIdx.x;
  constexpr int LF = 128*FSTR;     // u32 per layer's flag region
  if (b < 40){
    rec_stage<100, 0, 5, false>(a.G0, nullptr, a.Wh0, nullptr, 0,
        nullptr, a.Hx0, nullptr, a.flags + 0*LF, a.flags + 1*LF, 0, 5,
        a.cst + 0*128*200, nullptr, b & 7, b >> 3, a.t0, a.TC, a.Tlast, smem);
  } else if (b < 80){
    const int bb = b - 40;
    rec_stage<100, 128, 5, true>(nullptr, a.Wx1, a.Wh1, a.b1, 100,
        a.Hx0, a.Hx1, a.flags + 0*LF, a.flags + 1*LF, a.flags + 2*LF, 5, 10,
        a.cst + 1*128*200, nullptr, bb & 7, bb >> 3, a.t0, a.TC, a.Tlast, smem);
  } else if (b < 160){
    const int bb = b - 80;
    rec_stage<200, 128, 10, true>(nullptr, a.Wx2, a.Wh2, a.b2, 100,
        a.Hx1, a.Hx2, a.flags + 1*LF, a.flags + 2*LF, a.flags + 3*LF, 5, 10,
        a.cst + 2*128*200, nullptr, bb & 7, bb >> 3, a.t0, a.TC, a.Tlast, smem);
  } else {
    const int bb = b - 160;
    rec_stage<200, 224, 10, true>(nullptr, a.Wx3, a.Wh3, a.b3, 200,
        a.Hx2, a.Hx3, a.flags + 2*LF, a.flags + 3*LF, nullptr, 10, 0,
        a.cst + 3*128*200, a.hlast, bb & 7, bb >> 3, a.t0, a.TC, a.Tlast, smem);
  }
}

// ---------------------------------------------------------------------------
__global__ __launch_bounds__(256) void head_kernel(
    const float* __restrict__ hlast, const float* __restrict__ Wd,
    const float* __restrict__ bd, float* __restrict__ out)
{
  const int e = blockIdx.x*256 + threadIdx.x;
  if (e >= 128*6) return;
  const int b = e / 6, o = e - 6*b;
  float s = bd[o];
  const float* hp = hlast + (size_t)b*200;
  for (int k = 0; k < 200; ++k) s += hp[k] * Wd[k*6 + o];
  out[e] = s;
}

__global__ void fill_sentinel(float* out, int n){
  const int i = blockIdx.x*blockDim.x + threadIdx.x;
  if (i < n) out[i] = 1.0e30f;
}

// ---------------------------------------------------------------------------
extern "C" void kernel_launch(void* const* d_in, const int* in_sizes, int n_in,
                              void* d_out, int out_size, void* d_ws, size_t ws_size,
                              hipStream_t stream)
{
  (void)in_sizes; (void)n_in;
  const float* xs  = (const float*)d_in[0];
  const float* Wx[4] = {(const float*)d_in[1], (const float*)d_in[4],
                        (const float*)d_in[7], (const float*)d_in[10]};
  const float* Wh[4] = {(const float*)d_in[2], (const float*)d_in[5],
                        (const float*)d_in[8], (const float*)d_in[11]};
  const float* bs[4] = {(const float*)d_in[3], (const float*)d_in[6],
                        (const float*)d_in[9], (const float*)d_in[12]};
  const float* Wd = (const float*)d_in[13];
  const float* bd = (const float*)d_in[14];
  float* out = (float*)d_out;

  // ---- workspace layout ----
  char* ws = (char*)d_ws;
  const size_t HXU[4] = {131072, 131072, 229376, 229376};   // u32 per layer
  const size_t HX_TOT = HXU[0]+HXU[1]+HXU[2]+HXU[3];
  const size_t FLAGS_BYTES = (size_t)4*128*FSTR*4;          // 128 KiB
  size_t off = 0;
  const size_t OFF_FLAGS = off; off += FLAGS_BYTES;
  const size_t OFF_HX    = off; off += HX_TOT*4;
  const size_t OFF_CST   = off; off += (size_t)4*128*200*4;
  const size_t OFF_HLAST = off; off += (size_t)128*200*4;
  off = (off + 255) & ~(size_t)255;
  const size_t FIXED_END = off;

  int CT = 0;
  for (int ct = 1024; ct >= 8; ct >>= 1){
    const size_t need = FIXED_END + (size_t)ct*128*400*4;   // G0 chunk only
    if (ws_size >= need){ CT = ct; break; }
  }
  if (CT == 0){
    fill_sentinel<<<(out_size + 255)/256, 256, 0, stream>>>(out, out_size);
    return;
  }

  unsigned* flags = (unsigned*)(ws + OFF_FLAGS);
  unsigned* Hx0   = (unsigned*)(ws + OFF_HX);
  unsigned* Hx1   = Hx0 + HXU[0];
  unsigned* Hx2   = Hx1 + HXU[1];
  unsigned* Hx3   = Hx2 + HXU[2];
  float* cst      = (float*)(ws + OFF_CST);
  float* hlast    = (float*)(ws + OFF_HLAST);
  float* G0       = (float*)(ws + FIXED_END);

  // L3 stage LDS: 2 planes * 80*456 shorts = 145920 B + zbuf 16*81*4 = 5184
  const int FUSED_LDS = 151104;
  hipFuncSetAttribute(reinterpret_cast<const void*>(lstm_fused),
                      hipFuncAttributeMaxDynamicSharedMemorySize, FUSED_LDS);

  hipMemsetAsync(flags, 0, FLAGS_BYTES, stream);
  hipMemsetAsync(Hx0, 0, HX_TOT*4, stream);

  FusedArgs fa;
  fa.Wx1 = Wx[1]; fa.Wx2 = Wx[2]; fa.Wx3 = Wx[3];
  fa.Wh0 = Wh[0]; fa.Wh1 = Wh[1]; fa.Wh2 = Wh[2]; fa.Wh3 = Wh[3];
  fa.b1 = bs[1];  fa.b2 = bs[2];  fa.b3 = bs[3];
  fa.Hx0 = Hx0; fa.Hx1 = Hx1; fa.Hx2 = Hx2; fa.Hx3 = Hx3;
  fa.flags = flags; fa.cst = cst; fa.hlast = hlast;
  fa.G0 = G0; fa.Tlast = 1024;

  const int NC  = 1024 / CT;
  const int GMX = CT*128/256;
  for (int c = 0; c < NC; ++c){
    const int t0 = c*CT;
    gemm_pregate<<<dim3(GMX,5), 256, 0, stream>>>(xs + (size_t)t0*128, Wx[0], bs[0], G0,
        128, 4, 400, (size_t)128, (size_t)131072);
    fa.t0 = t0; fa.TC = CT;
    lstm_fused<<<240, 256, FUSED_LDS, stream>>>(fa);
  }

  head_kernel<<<3, 256, 0, stream>>>(hlast, Wd, bd, out);
}